// Round 2
// baseline (436.610 us; speedup 1.0000x reference)
//
#include <hip/hip_runtime.h>
#include <hip/hip_bf16.h>

typedef short bf16x8 __attribute__((ext_vector_type(8)));
typedef short bf16x4 __attribute__((ext_vector_type(4)));
typedef float f32x4 __attribute__((ext_vector_type(4)));
typedef unsigned short u16x8 __attribute__((ext_vector_type(8)));
typedef unsigned short u16x4 __attribute__((ext_vector_type(4)));

#define DEV static __device__ __forceinline__

DEV unsigned short f2bf(float f) {
  unsigned int u = __builtin_bit_cast(unsigned int, f);
  u += 0x7FFFu + ((u >> 16) & 1u);   // round-to-nearest-even
  return (unsigned short)(u >> 16);
}

// ---------------------------------------------------------------------------
// Projection GEMM: C[4096][1024] = X[4096][1024] @ W[1024][1024]^T + bias
// 128x128 tile, BK=64, 256 threads (4 waves), wave -> 64x64 quadrant.
// storeF=1 -> f32 output (qp, needed for residual); else bf16 output (kp,vp).
// ---------------------------------------------------------------------------
__global__ __launch_bounds__(256) void proj_kernel(
    const float* __restrict__ X, const float* __restrict__ W,
    const float* __restrict__ bias, float* __restrict__ outF,
    unsigned short* __restrict__ outB, int storeF)
{
  __shared__ unsigned short Asm[128][72];  // +8 pad: bank spread
  __shared__ unsigned short Bsm[128][72];
  const int t = threadIdx.x;
  const int lane = t & 63, wv = t >> 6;
  const int ln = lane & 15, g = lane >> 4;
  const int wr = wv >> 1, wc = wv & 1;
  const int m0 = blockIdx.y * 128, n0 = blockIdx.x * 128;

  f32x4 acc[4][4];
#pragma unroll
  for (int i = 0; i < 4; ++i)
#pragma unroll
    for (int j = 0; j < 4; ++j) acc[i][j] = {0.f, 0.f, 0.f, 0.f};

  const int rs = t >> 3, cs = (t & 7) * 8;
  for (int kt = 0; kt < 16; ++kt) {
    const int k0 = kt * 64;
    __syncthreads();
#pragma unroll
    for (int it = 0; it < 4; ++it) {
      const int r = rs + it * 32;
      const float* ga = X + (size_t)(m0 + r) * 1024 + k0 + cs;
      float4 a0 = *(const float4*)ga;
      float4 a1 = *(const float4*)(ga + 4);
      u16x8 pa = { f2bf(a0.x), f2bf(a0.y), f2bf(a0.z), f2bf(a0.w),
                   f2bf(a1.x), f2bf(a1.y), f2bf(a1.z), f2bf(a1.w) };
      *(u16x8*)&Asm[r][cs] = pa;
      const float* gb = W + (size_t)(n0 + r) * 1024 + k0 + cs;
      float4 b0 = *(const float4*)gb;
      float4 b1 = *(const float4*)(gb + 4);
      u16x8 pb = { f2bf(b0.x), f2bf(b0.y), f2bf(b0.z), f2bf(b0.w),
                   f2bf(b1.x), f2bf(b1.y), f2bf(b1.z), f2bf(b1.w) };
      *(u16x8*)&Bsm[r][cs] = pb;
    }
    __syncthreads();
#pragma unroll
    for (int ks = 0; ks < 2; ++ks) {
      bf16x8 af[4], bfr[4];
#pragma unroll
      for (int i = 0; i < 4; ++i) {
        af[i]  = *(const bf16x8*)&Asm[wr * 64 + i * 16 + ln][ks * 32 + g * 8];
        bfr[i] = *(const bf16x8*)&Bsm[wc * 64 + i * 16 + ln][ks * 32 + g * 8];
      }
#pragma unroll
      for (int i = 0; i < 4; ++i)
#pragma unroll
        for (int j = 0; j < 4; ++j)
          acc[i][j] = __builtin_amdgcn_mfma_f32_16x16x32_bf16(
              af[i], bfr[j], acc[i][j], 0, 0, 0);
    }
  }

  float bvv[4];
#pragma unroll
  for (int j = 0; j < 4; ++j) bvv[j] = bias[n0 + wc * 64 + j * 16 + ln];

#pragma unroll
  for (int i = 0; i < 4; ++i)
#pragma unroll
    for (int j = 0; j < 4; ++j)
#pragma unroll
      for (int r = 0; r < 4; ++r) {
        // C/D layout (HW-verified): col = lane&15, row = (lane>>4)*4 + r
        float v = acc[i][j][r] + bvv[j];
        int row = m0 + wr * 64 + i * 16 + g * 4 + r;
        int col = n0 + wc * 64 + j * 16 + ln;
        if (storeF) outF[(size_t)row * 1024 + col] = v;
        else        outB[(size_t)row * 1024 + col] = f2bf(v);
      }
}

// ---------------------------------------------------------------------------
// Attention: one block per (b, h, 32 q-rows). 512 threads = 8 waves.
// Wave w: m-half = w>>2 (16 rows), n-slot = w&3.
// Computes S^T = K*Q^T via MFMA so each lane holds P[m=lane&15][its k-set]
// entirely in registers -> softmax rows are lane-local + 2 shfl + LDS combine,
// and the PV A-fragment needs NO cross-lane movement.
// Writes residual (qp + ctx) directly into d_out[:B*L*D] (LN runs in-place).
// ---------------------------------------------------------------------------
struct G1 {
  unsigned short K[64][72];
  unsigned short Q[32][72];
  float red[2][16][4];
  float Tb[8][16][20];   // per-wave transpose tile for coalesced attn writes
};
struct G2 {
  unsigned short Vr[128][72];   // V chunk, row-major (coalesced staging)
  unsigned short Vt[64][136];   // V chunk, transposed [d][k] (+8 pad)
};
union SMem {
  G1 g1;
  G2 g2;
  float ctxp[4][32][64];        // cross-wave ctx partials
};

__global__ __launch_bounds__(512) void attn_kernel(
    const float* __restrict__ qp, const unsigned short* __restrict__ kp,
    const unsigned short* __restrict__ vp, const unsigned char* __restrict__ masks,
    float* __restrict__ attn_out, float* __restrict__ res_out)
{
  __shared__ SMem sm;
  const int t = threadIdx.x;
  const int wv = t >> 6, lane = t & 63;
  const int ln = lane & 15, g = lane >> 4;
  const int wq = wv & 3, wm = wv >> 2;
  const int b = blockIdx.z, h = blockIdx.y, m0 = blockIdx.x * 32;
  const size_t rowbase = (size_t)(b * 1024 + m0);

  // stage Q tile (32x64), f32 -> bf16
  {
    const int r = t >> 4, c4 = (t & 15) * 4;
    const float4 v = *(const float4*)(qp + (rowbase + r) * 1024 + h * 64 + c4);
    u16x4 p = { f2bf(v.x), f2bf(v.y), f2bf(v.z), f2bf(v.w) };
    *(u16x4*)&sm.g1.Q[r][c4] = p;
  }
  __syncthreads();

  bf16x8 qf[2];
#pragma unroll
  for (int dh = 0; dh < 2; ++dh)
    qf[dh] = *(const bf16x8*)&sm.g1.Q[wm * 16 + ln][dh * 32 + g * 8];

  f32x4 sc[16];
#pragma unroll
  for (int i = 0; i < 16; ++i) sc[i] = {0.f, 0.f, 0.f, 0.f};

  const int krs = t >> 3, kcs = (t & 7) * 8;
#pragma unroll
  for (int tt = 0; tt < 16; ++tt) {
    __syncthreads();
    *(u16x8*)&sm.g1.K[krs][kcs] =
        *(const u16x8*)(kp + ((size_t)(b * 1024) + tt * 64 + krs) * 1024 + h * 64 + kcs);
    __syncthreads();
#pragma unroll
    for (int dh = 0; dh < 2; ++dh) {
      bf16x8 kf = *(const bf16x8*)&sm.g1.K[wq * 16 + ln][dh * 32 + g * 8];
      sc[tt] = __builtin_amdgcn_mfma_f32_16x16x32_bf16(kf, qf[dh], sc[tt], 0, 0, 0);
    }
  }

  // ---- softmax (rows are lane-local: m = ln) ----
  const unsigned char* mrow = masks + ((size_t)b * 1024 + m0 + wm * 16 + ln) * 1024;
  float mx = -3.0e30f;
#pragma unroll
  for (int tt = 0; tt < 16; ++tt) {
#pragma unroll
    for (int r = 0; r < 4; ++r) sc[tt][r] *= 0.125f;   // 1/sqrt(64)
    unsigned mw = *(const unsigned*)(mrow + tt * 64 + wq * 16 + g * 4);
    if (mw) {
#pragma unroll
      for (int r = 0; r < 4; ++r)
        if ((mw >> (8 * r)) & 0xffu) sc[tt][r] = -1.0e30f;
    }
#pragma unroll
    for (int r = 0; r < 4; ++r) mx = fmaxf(mx, sc[tt][r]);
  }
  mx = fmaxf(mx, __shfl_xor(mx, 16));
  mx = fmaxf(mx, __shfl_xor(mx, 32));
  if (g == 0) sm.g1.red[wm][ln][wq] = mx;
  __syncthreads();
  mx = fmaxf(fmaxf(sm.g1.red[wm][ln][0], sm.g1.red[wm][ln][1]),
             fmaxf(sm.g1.red[wm][ln][2], sm.g1.red[wm][ln][3]));

  float sum = 0.f;
#pragma unroll
  for (int tt = 0; tt < 16; ++tt)
#pragma unroll
    for (int r = 0; r < 4; ++r) {
      float p = exp2f((sc[tt][r] - mx) * 1.4426950408889634f);
      sc[tt][r] = p;
      sum += p;
    }
  sum += __shfl_xor(sum, 16);
  sum += __shfl_xor(sum, 32);
  __syncthreads();                    // all red(max) reads done
  if (g == 0) sm.g1.red[wm][ln][wq] = sum;
  __syncthreads();
  float l4 = sm.g1.red[wm][ln][0] + sm.g1.red[wm][ln][1] +
             sm.g1.red[wm][ln][2] + sm.g1.red[wm][ln][3];
  float rinv = 1.0f / l4;
#pragma unroll
  for (int tt = 0; tt < 16; ++tt)
#pragma unroll
    for (int r = 0; r < 4; ++r) sc[tt][r] *= rinv;

  // ---- write normalized attention, coalesced via per-wave transpose tile ----
  {
    float* T = &sm.g1.Tb[wv][0][0];              // [16][20]
    const int mr = lane >> 2, ns = (lane & 3) * 4;
    const size_t abase = ((size_t)(b * 16 + h) * 1024 + (m0 + wm * 16));
#pragma unroll
    for (int tt = 0; tt < 16; ++tt) {
      *(f32x4*)&T[ln * 20 + g * 4] = sc[tt];     // wave-internal, in-order DS
      f32x4 vv = *(const f32x4*)&T[mr * 20 + ns];
      *(f32x4*)(attn_out + (abase + mr) * 1024 + tt * 64 + wq * 16 + ns) = vv;
    }
  }

  // ---- PV: ctx[m][d] += P[m][k] * V[k][d], lane-local A fragments ----
  f32x4 cacc[4];
#pragma unroll
  for (int i = 0; i < 4; ++i) cacc[i] = {0.f, 0.f, 0.f, 0.f};

  const int lk0 = wq * 16 + g * 4;
#pragma unroll
  for (int c = 0; c < 8; ++c) {
    __syncthreads();   // also protects G1 before first overwrite
#pragma unroll
    for (int p = 0; p < 2; ++p) {
      const int r = (t >> 3) + p * 64;
      *(u16x8*)&sm.g2.Vr[r][kcs] =
          *(const u16x8*)(vp + ((size_t)(b * 1024) + c * 128 + r) * 1024 + h * 64 + kcs);
    }
    __syncthreads();
    {
      const int d = t & 63, k0 = (t >> 6) * 16;
      u16x8 w0, w1;
#pragma unroll
      for (int i = 0; i < 8; ++i) w0[i] = sm.g2.Vr[k0 + i][d];
#pragma unroll
      for (int i = 0; i < 8; ++i) w1[i] = sm.g2.Vr[k0 + 8 + i][d];
      *(u16x8*)&sm.g2.Vt[d][k0] = w0;
      *(u16x8*)&sm.g2.Vt[d][k0 + 8] = w1;
    }
    __syncthreads();
    bf16x8 af;
#pragma unroll
    for (int r = 0; r < 4; ++r) af[r]     = (short)f2bf(sc[2 * c][r]);
#pragma unroll
    for (int r = 0; r < 4; ++r) af[4 + r] = (short)f2bf(sc[2 * c + 1][r]);
#pragma unroll
    for (int ni = 0; ni < 4; ++ni) {
      bf16x4 b0 = *(const bf16x4*)&sm.g2.Vt[ni * 16 + ln][lk0];
      bf16x4 b1 = *(const bf16x4*)&sm.g2.Vt[ni * 16 + ln][lk0 + 64];
      bf16x8 bfr = { b0[0], b0[1], b0[2], b0[3], b1[0], b1[1], b1[2], b1[3] };
      cacc[ni] = __builtin_amdgcn_mfma_f32_16x16x32_bf16(af, bfr, cacc[ni], 0, 0, 0);
    }
  }

  // ---- cross-wave ctx reduction, write residual qp+ctx into d_out ----
  __syncthreads();
#pragma unroll
  for (int ni = 0; ni < 4; ++ni)
#pragma unroll
    for (int r = 0; r < 4; ++r)
      sm.ctxp[wq][wm * 16 + g * 4 + r][ni * 16 + ln] = cacc[ni][r];
  __syncthreads();
  {
    const int m = t >> 4, d4 = (t & 15) * 4;
    f32x4 s0 = *(const f32x4*)&sm.ctxp[0][m][d4];
    f32x4 s1 = *(const f32x4*)&sm.ctxp[1][m][d4];
    f32x4 s2 = *(const f32x4*)&sm.ctxp[2][m][d4];
    f32x4 s3 = *(const f32x4*)&sm.ctxp[3][m][d4];
    f32x4 s = s0 + s1 + s2 + s3;
    f32x4 qv = *(const f32x4*)(qp + (rowbase + m) * 1024 + h * 64 + d4);
    s = s + qv;
    *(f32x4*)(res_out + (rowbase + m) * 1024 + h * 64 + d4) = s;
  }
}

// ---------------------------------------------------------------------------
// In-place LayerNorm on d_out[:B*L*D]: out = LN(out) * g + b, one block/row.
// ---------------------------------------------------------------------------
__global__ __launch_bounds__(256) void ln_kernel(
    float* __restrict__ io,
    const float* __restrict__ gma, const float* __restrict__ bta)
{
  __shared__ float rbuf[2][4];
  const int r = blockIdx.x, t = threadIdx.x;
  const int i4 = t * 4;
  const size_t base = (size_t)r * 1024 + i4;
  f32x4 x = *(const f32x4*)(io + base);
  float s = x[0] + x[1] + x[2] + x[3];
  float q = x[0]*x[0] + x[1]*x[1] + x[2]*x[2] + x[3]*x[3];
#pragma unroll
  for (int off = 1; off < 64; off <<= 1) {
    s += __shfl_xor(s, off);
    q += __shfl_xor(q, off);
  }
  const int wv = t >> 6;
  if ((t & 63) == 0) { rbuf[0][wv] = s; rbuf[1][wv] = q; }
  __syncthreads();
  s = rbuf[0][0] + rbuf[0][1] + rbuf[0][2] + rbuf[0][3];
  q = rbuf[1][0] + rbuf[1][1] + rbuf[1][2] + rbuf[1][3];
  float mu = s * (1.0f / 1024.0f);
  float var = q * (1.0f / 1024.0f) - mu * mu;
  float is = rsqrtf(var + 1e-6f);
  f32x4 gv = *(const f32x4*)(gma + i4);
  f32x4 bv = *(const f32x4*)(bta + i4);
  f32x4 o;
#pragma unroll
  for (int k = 0; k < 4; ++k) o[k] = (x[k] - mu) * is * gv[k] + bv[k];
  *(f32x4*)(io + base) = o;
}

// ---------------------------------------------------------------------------
extern "C" void kernel_launch(void* const* d_in, const int* in_sizes, int n_in,
                              void* d_out, int out_size, void* d_ws, size_t ws_size,
                              hipStream_t stream) {
  const float* q  = (const float*)d_in[0];
  const float* k  = (const float*)d_in[1];
  const float* v  = (const float*)d_in[2];
  const unsigned char* masks = (const unsigned char*)d_in[3];
  const float* Wq = (const float*)d_in[4];
  const float* bq = (const float*)d_in[5];
  const float* Wk = (const float*)d_in[6];
  const float* bk = (const float*)d_in[7];
  const float* Wv = (const float*)d_in[8];
  const float* bv = (const float*)d_in[9];
  const float* lg = (const float*)d_in[10];
  const float* lb = (const float*)d_in[11];

  float* out = (float*)d_out;
  float* attn_out = out + (size_t)4 * 1024 * 1024;

  // workspace: 32 MB total (qp f32 16MB | kp bf16 8MB | vp bf16 8MB)
  float* qp = (float*)d_ws;
  unsigned short* kp = (unsigned short*)((char*)d_ws + (size_t)(16 << 20));
  unsigned short* vp = (unsigned short*)((char*)d_ws + (size_t)(24 << 20));

  dim3 pgrid(8, 32);
  hipLaunchKernelGGL(proj_kernel, pgrid, dim3(256), 0, stream,
                     q, Wq, bq, qp, (unsigned short*)nullptr, 1);
  hipLaunchKernelGGL(proj_kernel, pgrid, dim3(256), 0, stream,
                     k, Wk, bk, (float*)nullptr, kp, 0);
  hipLaunchKernelGGL(proj_kernel, pgrid, dim3(256), 0, stream,
                     v, Wv, bv, (float*)nullptr, vp, 0);
  hipLaunchKernelGGL(attn_kernel, dim3(32, 16, 4), dim3(512), 0, stream,
                     qp, kp, vp, masks, attn_out, out);
  hipLaunchKernelGGL(ln_kernel, dim3(4096), dim3(256), 0, stream,
                     out, lg, lb);
}

// Round 3
// 313.533 us; speedup vs baseline: 1.3925x; 1.3925x over previous
//
#include <hip/hip_runtime.h>
#include <hip/hip_bf16.h>

typedef short bf16x8 __attribute__((ext_vector_type(8)));
typedef short bf16x4 __attribute__((ext_vector_type(4)));
typedef float f32x4 __attribute__((ext_vector_type(4)));
typedef unsigned short u16x8 __attribute__((ext_vector_type(8)));
typedef unsigned short u16x4 __attribute__((ext_vector_type(4)));

#define DEV static __device__ __forceinline__

DEV unsigned short f2bf(float f) {
  unsigned int u = __builtin_bit_cast(unsigned int, f);
  u += 0x7FFFu + ((u >> 16) & 1u);   // round-to-nearest-even
  return (unsigned short)(u >> 16);
}

// ---------------------------------------------------------------------------
// Projection GEMM: C[4096][1024] = X[4096][1024] @ W[1024][1024]^T + bias
// 64x64 tile, BK=64, 256 threads (4 waves), wave -> 32x32 quadrant.
// grid = flat 1024 blocks (4 resident/CU), XCD-swizzled so blocks sharing a
// W-strip cluster on one XCD.
// mode 0: bf16 row-major (K). mode 1: f32 row-major (Q, residual needs f32).
// mode 2: bf16 TRANSPOSED per-head (V): outT[((b*16+h)*64+dh)*1024 + token].
// ---------------------------------------------------------------------------
__global__ __launch_bounds__(256) void proj_kernel(
    const float* __restrict__ X, const float* __restrict__ W,
    const float* __restrict__ bias, float* __restrict__ outF,
    unsigned short* __restrict__ outB, unsigned short* __restrict__ outT,
    int mode)
{
  __shared__ union {
    struct { unsigned short A[64][72]; unsigned short B[64][72]; } s;
    unsigned short T[64][72];          // V-transpose epilogue scratch
  } sm;
  const int t = threadIdx.x;
  const int lane = t & 63, wv = t >> 6;
  const int ln = lane & 15, g = lane >> 4;
  const int wr = wv >> 1, wc = wv & 1;
  const int hw = blockIdx.x;
  const int lid = (hw & 7) * 128 + (hw >> 3);   // bijective XCD swizzle
  const int n0 = (lid >> 6) * 64;               // 16 W-strips
  const int m0 = (lid & 63) * 64;               // 64 token-tiles

  f32x4 acc[2][2];
#pragma unroll
  for (int i = 0; i < 2; ++i)
#pragma unroll
    for (int j = 0; j < 2; ++j) acc[i][j] = {0.f, 0.f, 0.f, 0.f};

  const int r = t >> 2, c16 = (t & 3) * 16;
  for (int kt = 0; kt < 16; ++kt) {
    const int k0 = kt * 64;
    __syncthreads();
    {
      const float* ga = X + (size_t)(m0 + r) * 1024 + k0 + c16;
      float4 a0 = *(const float4*)ga;
      float4 a1 = *(const float4*)(ga + 4);
      float4 a2 = *(const float4*)(ga + 8);
      float4 a3 = *(const float4*)(ga + 12);
      u16x8 p0 = { f2bf(a0.x), f2bf(a0.y), f2bf(a0.z), f2bf(a0.w),
                   f2bf(a1.x), f2bf(a1.y), f2bf(a1.z), f2bf(a1.w) };
      u16x8 p1 = { f2bf(a2.x), f2bf(a2.y), f2bf(a2.z), f2bf(a2.w),
                   f2bf(a3.x), f2bf(a3.y), f2bf(a3.z), f2bf(a3.w) };
      *(u16x8*)&sm.s.A[r][c16] = p0;
      *(u16x8*)&sm.s.A[r][c16 + 8] = p1;
      const float* gb = W + (size_t)(n0 + r) * 1024 + k0 + c16;
      float4 b0 = *(const float4*)gb;
      float4 b1 = *(const float4*)(gb + 4);
      float4 b2 = *(const float4*)(gb + 8);
      float4 b3 = *(const float4*)(gb + 12);
      u16x8 q0 = { f2bf(b0.x), f2bf(b0.y), f2bf(b0.z), f2bf(b0.w),
                   f2bf(b1.x), f2bf(b1.y), f2bf(b1.z), f2bf(b1.w) };
      u16x8 q1 = { f2bf(b2.x), f2bf(b2.y), f2bf(b2.z), f2bf(b2.w),
                   f2bf(b3.x), f2bf(b3.y), f2bf(b3.z), f2bf(b3.w) };
      *(u16x8*)&sm.s.B[r][c16] = q0;
      *(u16x8*)&sm.s.B[r][c16 + 8] = q1;
    }
    __syncthreads();
#pragma unroll
    for (int ks = 0; ks < 2; ++ks) {
      bf16x8 af[2], bfr[2];
#pragma unroll
      for (int i = 0; i < 2; ++i) {
        af[i]  = *(const bf16x8*)&sm.s.A[wr * 32 + i * 16 + ln][ks * 32 + g * 8];
        bfr[i] = *(const bf16x8*)&sm.s.B[wc * 32 + i * 16 + ln][ks * 32 + g * 8];
      }
#pragma unroll
      for (int i = 0; i < 2; ++i)
#pragma unroll
        for (int j = 0; j < 2; ++j)
          acc[i][j] = __builtin_amdgcn_mfma_f32_16x16x32_bf16(
              af[i], bfr[j], acc[i][j], 0, 0, 0);
    }
  }

  float bvv[2];
#pragma unroll
  for (int j = 0; j < 2; ++j) bvv[j] = bias[n0 + wc * 32 + j * 16 + ln];

  if (mode == 2) {
    // transpose in LDS, store per-head transposed: vt[(b*16+h)*64+dh][token]
    __syncthreads();
#pragma unroll
    for (int i = 0; i < 2; ++i)
#pragma unroll
      for (int j = 0; j < 2; ++j) {
        u16x4 p = { f2bf(acc[i][j][0] + bvv[j]), f2bf(acc[i][j][1] + bvv[j]),
                    f2bf(acc[i][j][2] + bvv[j]), f2bf(acc[i][j][3] + bvv[j]) };
        // C/D layout: col = lane&15, row = (lane>>4)*4 + reg (consecutive rows)
        *(u16x4*)&sm.T[wc * 32 + j * 16 + ln][wr * 32 + i * 16 + g * 4] = p;
      }
    __syncthreads();
    const int bb = m0 >> 10, h = n0 >> 6, l0 = m0 & 1023;
#pragma unroll
    for (int it = 0; it < 2; ++it) {
      const int dh = (t >> 3) + it * 32;
      const int l8 = (t & 7) * 8;
      *(u16x8*)&outT[((size_t)(bb * 16 + h) * 64 + dh) * 1024 + l0 + l8] =
          *(const u16x8*)&sm.T[dh][l8];
    }
  } else {
#pragma unroll
    for (int i = 0; i < 2; ++i)
#pragma unroll
      for (int j = 0; j < 2; ++j)
#pragma unroll
        for (int rr = 0; rr < 4; ++rr) {
          float v = acc[i][j][rr] + bvv[j];
          int row = m0 + wr * 32 + i * 16 + g * 4 + rr;
          int col = n0 + wc * 32 + j * 16 + ln;
          if (mode == 1) outF[(size_t)row * 1024 + col] = v;
          else           outB[(size_t)row * 1024 + col] = f2bf(v);
        }
  }
}

// ---------------------------------------------------------------------------
// Attention: one block per (b, h, 32 q-rows). 512 threads = 8 waves.
// S^T = K*Q^T so softmax rows are lane-local; PV A-frags need no cross-lane
// movement (validated mapping). K and V^T staged register->LDS with double
// buffering: 1 barrier per chunk, global-load latency hidden under MFMA.
// V^T comes pre-transposed from proj (mode 2). Residual qp+ctx written to
// d_out; attention written (normalized) after PV via dbuf transpose tiles.
// ---------------------------------------------------------------------------
struct PhA {
  unsigned short K[2][64][72];     // dbuf K chunks
  unsigned short Q[32][72];
};
struct PhB {
  unsigned short Vt[2][64][136];   // dbuf V^T chunks [d][k], 128-k chunks
};
union SMemU {
  PhA a;
  PhB b;
  float Tb[8][2][16][20];          // per-wave dbuf transpose tiles (attn write)
  float ctxp[4][32][64];           // cross-wave ctx partials
};

__global__ __launch_bounds__(512) void attn_kernel(
    const float* __restrict__ qp, const unsigned short* __restrict__ kp,
    const unsigned short* __restrict__ vt, const unsigned char* __restrict__ masks,
    float* __restrict__ attn_out, float* __restrict__ res_out)
{
  __shared__ SMemU sm;
  __shared__ float red[2][16][4];
  const int t = threadIdx.x;
  const int wv = t >> 6, lane = t & 63;
  const int ln = lane & 15, g = lane >> 4;
  const int wq = wv & 3, wm = wv >> 2;
  const int hw = blockIdx.x;
  const int lid = (hw & 7) * 256 + (hw >> 3);  // cluster same-(b,h) per XCD
  const int b = lid >> 9, h = (lid >> 5) & 15, m0 = (lid & 31) * 32;
  const size_t rowbase = (size_t)(b * 1024 + m0);

  const int krow = t >> 3, kcol = (t & 7) * 8;
  const unsigned short* kbase = kp + ((size_t)b * 1024) * 1024 + h * 64;

  // prologue: issue K chunk-0 load, stage Q
  u16x8 kreg = *(const u16x8*)(kbase + (size_t)krow * 1024 + kcol);
  {
    const int r = t >> 4, c4 = (t & 15) * 4;
    const float4 v = *(const float4*)(qp + (rowbase + r) * 1024 + h * 64 + c4);
    u16x4 p = { f2bf(v.x), f2bf(v.y), f2bf(v.z), f2bf(v.w) };
    *(u16x4*)&sm.a.Q[r][c4] = p;
  }
  __syncthreads();

  bf16x8 qf[2];
#pragma unroll
  for (int dh = 0; dh < 2; ++dh)
    qf[dh] = *(const bf16x8*)&sm.a.Q[wm * 16 + ln][dh * 32 + g * 8];

  f32x4 sc[16];
#pragma unroll
  for (int i = 0; i < 16; ++i) sc[i] = {0.f, 0.f, 0.f, 0.f};

  // ---- QK^T: dbuf reg-staged K, 1 barrier per 64-row chunk ----
#pragma unroll
  for (int tt = 0; tt < 16; ++tt) {
    *(u16x8*)&sm.a.K[tt & 1][krow][kcol] = kreg;
    if (tt < 15)
      kreg = *(const u16x8*)(kbase + (size_t)((tt + 1) * 64 + krow) * 1024 + kcol);
    __syncthreads();
    bf16x8 kf0 = *(const bf16x8*)&sm.a.K[tt & 1][wq * 16 + ln][g * 8];
    bf16x8 kf1 = *(const bf16x8*)&sm.a.K[tt & 1][wq * 16 + ln][32 + g * 8];
    sc[tt] = __builtin_amdgcn_mfma_f32_16x16x32_bf16(kf0, qf[0], sc[tt], 0, 0, 0);
    sc[tt] = __builtin_amdgcn_mfma_f32_16x16x32_bf16(kf1, qf[1], sc[tt], 0, 0, 0);
  }

  // issue V chunk-0 loads early; latency hides under softmax
  const unsigned short* vbase = vt + ((size_t)(b * 16 + h) * 64) * 1024;
  u16x8 vreg0 = *(const u16x8*)(vbase + (size_t)krow * 1024 + kcol);
  u16x8 vreg1 = *(const u16x8*)(vbase + (size_t)krow * 1024 + 64 + kcol);

  // ---- softmax (rows lane-local: q-row = ln) ----
  const unsigned char* mrow = masks + ((size_t)b * 1024 + m0 + wm * 16 + ln) * 1024;
  float mx = -3.0e30f;
#pragma unroll
  for (int tt = 0; tt < 16; ++tt) {
#pragma unroll
    for (int r = 0; r < 4; ++r) sc[tt][r] *= 0.125f;   // 1/sqrt(64)
    unsigned mw = *(const unsigned*)(mrow + tt * 64 + wq * 16 + g * 4);
    if (mw) {
#pragma unroll
      for (int r = 0; r < 4; ++r)
        if ((mw >> (8 * r)) & 0xffu) sc[tt][r] = -1.0e30f;
    }
#pragma unroll
    for (int r = 0; r < 4; ++r) mx = fmaxf(mx, sc[tt][r]);
  }
  mx = fmaxf(mx, __shfl_xor(mx, 16));
  mx = fmaxf(mx, __shfl_xor(mx, 32));
  if (g == 0) red[wm][ln][wq] = mx;
  __syncthreads();
  mx = fmaxf(fmaxf(red[wm][ln][0], red[wm][ln][1]),
             fmaxf(red[wm][ln][2], red[wm][ln][3]));

  float sum = 0.f;
#pragma unroll
  for (int tt = 0; tt < 16; ++tt)
#pragma unroll
    for (int r = 0; r < 4; ++r) {
      float p = exp2f((sc[tt][r] - mx) * 1.4426950408889634f);
      sc[tt][r] = p;
      sum += p;
    }
  sum += __shfl_xor(sum, 16);
  sum += __shfl_xor(sum, 32);
  __syncthreads();                    // all red(max) reads done
  if (g == 0) red[wm][ln][wq] = sum;
  __syncthreads();
  float l4 = red[wm][ln][0] + red[wm][ln][1] +
             red[wm][ln][2] + red[wm][ln][3];
  float rinv = 1.0f / l4;
#pragma unroll
  for (int tt = 0; tt < 16; ++tt)
#pragma unroll
    for (int r = 0; r < 4; ++r) sc[tt][r] *= rinv;

  // ---- PV: dbuf reg-staged V^T, 1 barrier per 128-k chunk ----
  f32x4 cacc[4];
#pragma unroll
  for (int i = 0; i < 4; ++i) cacc[i] = {0.f, 0.f, 0.f, 0.f};

  const int lk0 = wq * 16 + g * 4;
#pragma unroll
  for (int c = 0; c < 8; ++c) {
    *(u16x8*)&sm.b.Vt[c & 1][krow][kcol] = vreg0;
    *(u16x8*)&sm.b.Vt[c & 1][krow][64 + kcol] = vreg1;
    if (c < 7) {
      vreg0 = *(const u16x8*)(vbase + (size_t)krow * 1024 + (c + 1) * 128 + kcol);
      vreg1 = *(const u16x8*)(vbase + (size_t)krow * 1024 + (c + 1) * 128 + 64 + kcol);
    }
    __syncthreads();
    bf16x8 af;
#pragma unroll
    for (int r = 0; r < 4; ++r) af[r]     = (short)f2bf(sc[2 * c][r]);
#pragma unroll
    for (int r = 0; r < 4; ++r) af[4 + r] = (short)f2bf(sc[2 * c + 1][r]);
#pragma unroll
    for (int ni = 0; ni < 4; ++ni) {
      bf16x4 b0 = *(const bf16x4*)&sm.b.Vt[c & 1][ni * 16 + ln][lk0];
      bf16x4 b1 = *(const bf16x4*)&sm.b.Vt[c & 1][ni * 16 + ln][64 + lk0];
      bf16x8 bfr = { b0[0], b0[1], b0[2], b0[3], b1[0], b1[1], b1[2], b1[3] };
      cacc[ni] = __builtin_amdgcn_mfma_f32_16x16x32_bf16(af, bfr, cacc[ni], 0, 0, 0);
    }
  }

  // ---- cross-wave ctx reduction + residual -> d_out ----
  __syncthreads();                    // Vt reads done; reuse LDS as ctxp
#pragma unroll
  for (int ni = 0; ni < 4; ++ni)
#pragma unroll
    for (int r = 0; r < 4; ++r)
      sm.ctxp[wq][wm * 16 + g * 4 + r][ni * 16 + ln] = cacc[ni][r];
  __syncthreads();
  {
    const int m = t >> 4, d4 = (t & 15) * 4;
    f32x4 s0 = *(const f32x4*)&sm.ctxp[0][m][d4];
    f32x4 s1 = *(const f32x4*)&sm.ctxp[1][m][d4];
    f32x4 s2 = *(const f32x4*)&sm.ctxp[2][m][d4];
    f32x4 s3 = *(const f32x4*)&sm.ctxp[3][m][d4];
    f32x4 s = s0 + s1 + s2 + s3;
    f32x4 qv = *(const f32x4*)(qp + (rowbase + m) * 1024 + h * 64 + d4);
    s = s + qv;
    *(f32x4*)(res_out + (rowbase + m) * 1024 + h * 64 + d4) = s;
  }

  // ---- write normalized attention via per-wave dbuf transpose tiles ----
  __syncthreads();                    // ctxp reads done; reuse LDS as Tb
  {
    const int mr = lane >> 2, ns = (lane & 3) * 4;
    const size_t abase = ((size_t)(b * 16 + h) * 1024 + (m0 + wm * 16));
#pragma unroll
    for (int tt = 0; tt < 16; ++tt) {
      float* T = &sm.Tb[wv][tt & 1][0][0];       // [16][20]
      *(f32x4*)&T[ln * 20 + g * 4] = sc[tt];     // wave-internal, in-order DS
      f32x4 vv = *(const f32x4*)&T[mr * 20 + ns];
      *(f32x4*)(attn_out + (abase + mr) * 1024 + tt * 64 + wq * 16 + ns) = vv;
    }
  }
}

// ---------------------------------------------------------------------------
// In-place LayerNorm on d_out[:B*L*D]: out = LN(out) * g + b, one block/row.
// ---------------------------------------------------------------------------
__global__ __launch_bounds__(256) void ln_kernel(
    float* __restrict__ io,
    const float* __restrict__ gma, const float* __restrict__ bta)
{
  __shared__ float rbuf[2][4];
  const int r = blockIdx.x, t = threadIdx.x;
  const int i4 = t * 4;
  const size_t base = (size_t)r * 1024 + i4;
  f32x4 x = *(const f32x4*)(io + base);
  float s = x[0] + x[1] + x[2] + x[3];
  float q = x[0]*x[0] + x[1]*x[1] + x[2]*x[2] + x[3]*x[3];
#pragma unroll
  for (int off = 1; off < 64; off <<= 1) {
    s += __shfl_xor(s, off);
    q += __shfl_xor(q, off);
  }
  const int wv = t >> 6;
  if ((t & 63) == 0) { rbuf[0][wv] = s; rbuf[1][wv] = q; }
  __syncthreads();
  s = rbuf[0][0] + rbuf[0][1] + rbuf[0][2] + rbuf[0][3];
  q = rbuf[1][0] + rbuf[1][1] + rbuf[1][2] + rbuf[1][3];
  float mu = s * (1.0f / 1024.0f);
  float var = q * (1.0f / 1024.0f) - mu * mu;
  float is = rsqrtf(var + 1e-6f);
  f32x4 gv = *(const f32x4*)(gma + i4);
  f32x4 bv = *(const f32x4*)(bta + i4);
  f32x4 o;
#pragma unroll
  for (int k = 0; k < 4; ++k) o[k] = (x[k] - mu) * is * gv[k] + bv[k];
  *(f32x4*)(io + base) = o;
}

// ---------------------------------------------------------------------------
extern "C" void kernel_launch(void* const* d_in, const int* in_sizes, int n_in,
                              void* d_out, int out_size, void* d_ws, size_t ws_size,
                              hipStream_t stream) {
  const float* q  = (const float*)d_in[0];
  const float* k  = (const float*)d_in[1];
  const float* v  = (const float*)d_in[2];
  const unsigned char* masks = (const unsigned char*)d_in[3];
  const float* Wq = (const float*)d_in[4];
  const float* bq = (const float*)d_in[5];
  const float* Wk = (const float*)d_in[6];
  const float* bk = (const float*)d_in[7];
  const float* Wv = (const float*)d_in[8];
  const float* bv = (const float*)d_in[9];
  const float* lg = (const float*)d_in[10];
  const float* lb = (const float*)d_in[11];

  float* out = (float*)d_out;
  float* attn_out = out + (size_t)4 * 1024 * 1024;

  // workspace: 32 MB total (qp f32 16MB | kp bf16 8MB | vt bf16 8MB)
  float* qp = (float*)d_ws;
  unsigned short* kp = (unsigned short*)((char*)d_ws + (size_t)(16 << 20));
  unsigned short* vt = (unsigned short*)((char*)d_ws + (size_t)(24 << 20));

  hipLaunchKernelGGL(proj_kernel, dim3(1024), dim3(256), 0, stream,
                     q, Wq, bq, qp, (unsigned short*)nullptr,
                     (unsigned short*)nullptr, 1);
  hipLaunchKernelGGL(proj_kernel, dim3(1024), dim3(256), 0, stream,
                     k, Wk, bk, (float*)nullptr, kp,
                     (unsigned short*)nullptr, 0);
  hipLaunchKernelGGL(proj_kernel, dim3(1024), dim3(256), 0, stream,
                     v, Wv, bv, (float*)nullptr, (unsigned short*)nullptr,
                     vt, 2);
  hipLaunchKernelGGL(attn_kernel, dim3(2048), dim3(512), 0, stream,
                     qp, kp, vt, masks, attn_out, out);
  hipLaunchKernelGGL(ln_kernel, dim3(4096), dim3(256), 0, stream,
                     out, lg, lb);
}

// Round 4
// 307.832 us; speedup vs baseline: 1.4183x; 1.0185x over previous
//
#include <hip/hip_runtime.h>
#include <hip/hip_bf16.h>

typedef short bf16x8 __attribute__((ext_vector_type(8)));
typedef short bf16x4 __attribute__((ext_vector_type(4)));
typedef float f32x4 __attribute__((ext_vector_type(4)));
typedef unsigned short u16x8 __attribute__((ext_vector_type(8)));
typedef unsigned short u16x4 __attribute__((ext_vector_type(4)));

#define DEV static __device__ __forceinline__

DEV unsigned short f2bf(float f) {
  unsigned int u = __builtin_bit_cast(unsigned int, f);
  u += 0x7FFFu + ((u >> 16) & 1u);   // round-to-nearest-even
  return (unsigned short)(u >> 16);
}
DEV float bf2f(unsigned short u) {
  return __builtin_bit_cast(float, (unsigned int)u << 16);
}

DEV void gload_lds16(const unsigned short* g, unsigned short* l) {
  __builtin_amdgcn_global_load_lds(
      (const __attribute__((address_space(1))) unsigned int*)g,
      (__attribute__((address_space(3))) unsigned int*)l, 16, 0, 0);
}

// ---------------------------------------------------------------------------
// Convert pass: f32 -> bf16 for q,k,v (4M elems each) and Wq,Wk,Wv (1M each).
// 8 elems/thread. Segment boundaries in 8-elem units.
// ---------------------------------------------------------------------------
__global__ __launch_bounds__(256) void cvt_kernel(
    const float* __restrict__ q, const float* __restrict__ k,
    const float* __restrict__ v, const float* __restrict__ wq,
    const float* __restrict__ wk, const float* __restrict__ wv,
    unsigned short* __restrict__ xq, unsigned short* __restrict__ xk,
    unsigned short* __restrict__ xv, unsigned short* __restrict__ wqb,
    unsigned short* __restrict__ wkb, unsigned short* __restrict__ wvb)
{
  int tid = blockIdx.x * 256 + threadIdx.x;
  const float* src; unsigned short* dst; int off;
  if      (tid <  524288) { src = q;  dst = xq;  off = tid; }
  else if (tid < 1048576) { src = k;  dst = xk;  off = tid -  524288; }
  else if (tid < 1572864) { src = v;  dst = xv;  off = tid - 1048576; }
  else if (tid < 1703936) { src = wq; dst = wqb; off = tid - 1572864; }
  else if (tid < 1835008) { src = wk; dst = wkb; off = tid - 1703936; }
  else                    { src = wv; dst = wvb; off = tid - 1835008; }
  size_t e = (size_t)off * 8;
  float4 a = *(const float4*)(src + e);
  float4 b = *(const float4*)(src + e + 4);
  u16x8 p = { f2bf(a.x), f2bf(a.y), f2bf(a.z), f2bf(a.w),
              f2bf(b.x), f2bf(b.y), f2bf(b.z), f2bf(b.w) };
  *(u16x8*)(dst + e) = p;
}

// ---------------------------------------------------------------------------
// Fused projection GEMMs: seg = blockIdx>>8 picks (X, W, bias, out, mode).
// C[4096][1024] = X @ W^T + bias, bf16 in/out. 128x128 tile, BK=64,
// 512 threads (8 waves, 2m x 4n), global_load_lds 16B staging.
// mode 0: bf16 row-major. mode 2: bf16 transposed per-head (V).
// ---------------------------------------------------------------------------
__global__ __launch_bounds__(512) void gemm_kernel(
    const unsigned short* __restrict__ xq, const unsigned short* __restrict__ xk,
    const unsigned short* __restrict__ xv, const unsigned short* __restrict__ wqb,
    const unsigned short* __restrict__ wkb, const unsigned short* __restrict__ wvb,
    const float* __restrict__ bq, const float* __restrict__ bk,
    const float* __restrict__ bv, unsigned short* __restrict__ qp,
    unsigned short* __restrict__ kp, unsigned short* __restrict__ vt)
{
  __shared__ union {
    struct { unsigned short A[128][64]; unsigned short B[128][64]; } ab;
    unsigned short T[128][128];
  } smu;
  const int t = threadIdx.x, lane = t & 63, wv8 = t >> 6;
  const int ln = lane & 15, g = lane >> 4;
  const int wm2 = wv8 >> 2, wn4 = wv8 & 3;
  const int seg = blockIdx.x >> 8, lb = blockIdx.x & 255;
  const int n0 = (lb & 7) * 128, m0 = (lb >> 3) * 128;

  const unsigned short* X; const unsigned short* W; const float* bias;
  unsigned short* outR; int mode;
  if (seg == 0)      { X = xq; W = wqb; bias = bq; outR = qp; mode = 0; }
  else if (seg == 1) { X = xk; W = wkb; bias = bk; outR = kp; mode = 0; }
  else               { X = xv; W = wvb; bias = bv; outR = vt; mode = 2; }

  f32x4 acc[4][2];
#pragma unroll
  for (int i = 0; i < 4; ++i)
#pragma unroll
    for (int j = 0; j < 2; ++j) acc[i][j] = {0.f, 0.f, 0.f, 0.f};

  const int lrow = lane >> 3, lcol = (lane & 7) * 8;
  for (int kt = 0; kt < 16; ++kt) {
    const int k0 = kt * 64;
    __syncthreads();
#pragma unroll
    for (int i = 0; i < 2; ++i) {
      const int r = wv8 * 16 + i * 8;
      gload_lds16(X + (size_t)(m0 + r + lrow) * 1024 + k0 + lcol, &smu.ab.A[r][0]);
      gload_lds16(W + (size_t)(n0 + r + lrow) * 1024 + k0 + lcol, &smu.ab.B[r][0]);
    }
    __syncthreads();
#pragma unroll
    for (int ks = 0; ks < 2; ++ks) {
      bf16x8 af[4], bfr[2];
#pragma unroll
      for (int i = 0; i < 4; ++i)
        af[i] = *(const bf16x8*)&smu.ab.A[wm2 * 64 + i * 16 + ln][ks * 32 + g * 8];
#pragma unroll
      for (int j = 0; j < 2; ++j)
        bfr[j] = *(const bf16x8*)&smu.ab.B[wn4 * 32 + j * 16 + ln][ks * 32 + g * 8];
#pragma unroll
      for (int i = 0; i < 4; ++i)
#pragma unroll
        for (int j = 0; j < 2; ++j)
          acc[i][j] = __builtin_amdgcn_mfma_f32_16x16x32_bf16(
              af[i], bfr[j], acc[i][j], 0, 0, 0);
    }
  }

  float bvv[2];
#pragma unroll
  for (int j = 0; j < 2; ++j) bvv[j] = bias[n0 + wn4 * 32 + j * 16 + ln];

  if (mode == 0) {
#pragma unroll
    for (int i = 0; i < 4; ++i)
#pragma unroll
      for (int j = 0; j < 2; ++j)
#pragma unroll
        for (int r = 0; r < 4; ++r) {
          int row = m0 + wm2 * 64 + i * 16 + g * 4 + r;
          int col = n0 + wn4 * 32 + j * 16 + ln;
          outR[(size_t)row * 1024 + col] = f2bf(acc[i][j][r] + bvv[j]);
        }
  } else {
    __syncthreads();   // A/B reads done; reuse LDS as T
#pragma unroll
    for (int i = 0; i < 4; ++i)
#pragma unroll
      for (int j = 0; j < 2; ++j)
#pragma unroll
        for (int r = 0; r < 4; ++r)
          smu.T[wn4 * 32 + j * 16 + ln][wm2 * 64 + i * 16 + g * 4 + r] =
              f2bf(acc[i][j][r] + bvv[j]);
    __syncthreads();
    const int bb = m0 >> 10, l0 = m0 & 1023;
#pragma unroll
    for (int it = 0; it < 4; ++it) {
      const int col = it * 32 + (t >> 4);
      const int r8 = (t & 15) * 8;
      *(u16x8*)&outR[((size_t)(bb * 16 + (n0 >> 6) + (col >> 6)) * 64 + (col & 63)) * 1024 + l0 + r8] =
          *(const u16x8*)&smu.T[col][r8];
    }
  }
}

// ---------------------------------------------------------------------------
// Attention: one block per (b, h, 32 q-rows). 512 threads = 8 waves.
// S^T = K*Q^T (validated mapping) so softmax rows are lane-local and PV
// A-frags need no cross-lane movement. K/V/Q fragments loaded DIRECTLY from
// global into registers (contiguous 16B/8B segments) with static software
// pipelines -> zero staging barriers. LDS only for red/Tb/ctxp.
// ---------------------------------------------------------------------------
union SMemU {
  float Tb[8][2][16][20];          // per-wave dbuf transpose tiles (attn write)
  float ctxp[4][32][64];           // cross-wave ctx partials
};

__global__ __launch_bounds__(512, 2) void attn_kernel(
    const unsigned short* __restrict__ qp, const unsigned short* __restrict__ kp,
    const unsigned short* __restrict__ vt, const unsigned char* __restrict__ masks,
    float* __restrict__ attn_out, float* __restrict__ res_out)
{
  __shared__ SMemU sm;
  __shared__ float red[2][16][4];
  const int t = threadIdx.x;
  const int wv = t >> 6, lane = t & 63;
  const int ln = lane & 15, g = lane >> 4;
  const int wq = wv & 3, wm = wv >> 2;
  const int hw = blockIdx.x;
  const int lid = (hw & 7) * 256 + (hw >> 3);  // cluster same-(b,h) per XCD
  const int b = lid >> 9, h = (lid >> 5) & 15, m0 = (lid & 31) * 32;
  const size_t rowbase = (size_t)(b * 1024 + m0);

  // Q fragments: direct global (bf16), 2 x 16B per lane
  bf16x8 qf[2];
  {
    const unsigned short* qb =
        qp + (rowbase + wm * 16 + ln) * 1024 + h * 64 + g * 8;
    qf[0] = *(const bf16x8*)qb;
    qf[1] = *(const bf16x8*)(qb + 32);
  }

  f32x4 sc[16];
#pragma unroll
  for (int i = 0; i < 16; ++i) sc[i] = {0.f, 0.f, 0.f, 0.f};

  // ---- QK^T: direct-global K fragments, depth-3 static pipeline ----
  {
    const unsigned short* kb =
        kp + ((size_t)(b * 1024) + wq * 16 + ln) * 1024 + h * 64 + g * 8;
    bf16x8 k0r[3], k1r[3];
#pragma unroll
    for (int p = 0; p < 3; ++p) {
      k0r[p] = *(const bf16x8*)(kb + (size_t)p * 65536);
      k1r[p] = *(const bf16x8*)(kb + (size_t)p * 65536 + 32);
    }
#pragma unroll
    for (int tt = 0; tt < 16; ++tt) {
      const int s = tt % 3;   // compile-time under full unroll
      sc[tt] = __builtin_amdgcn_mfma_f32_16x16x32_bf16(k0r[s], qf[0], sc[tt], 0, 0, 0);
      sc[tt] = __builtin_amdgcn_mfma_f32_16x16x32_bf16(k1r[s], qf[1], sc[tt], 0, 0, 0);
      if (tt + 3 < 16) {
        k0r[s] = *(const bf16x8*)(kb + (size_t)(tt + 3) * 65536);
        k1r[s] = *(const bf16x8*)(kb + (size_t)(tt + 3) * 65536 + 32);
      }
    }
  }

  // ---- masks (independent loads, issue early) ----
  unsigned mw[16];
  {
    const unsigned char* mrow =
        masks + ((size_t)b * 1024 + m0 + wm * 16 + ln) * 1024 + wq * 16 + g * 4;
#pragma unroll
    for (int tt = 0; tt < 16; ++tt) mw[tt] = *(const unsigned*)(mrow + tt * 64);
  }

  // ---- softmax (rows lane-local: q-row = ln) ----
  float mx = -3.0e30f;
#pragma unroll
  for (int tt = 0; tt < 16; ++tt) {
#pragma unroll
    for (int r = 0; r < 4; ++r) sc[tt][r] *= 0.125f;   // 1/sqrt(64)
    if (mw[tt]) {
#pragma unroll
      for (int r = 0; r < 4; ++r)
        if ((mw[tt] >> (8 * r)) & 0xffu) sc[tt][r] = -1.0e30f;
    }
#pragma unroll
    for (int r = 0; r < 4; ++r) mx = fmaxf(mx, sc[tt][r]);
  }
  mx = fmaxf(mx, __shfl_xor(mx, 16));
  mx = fmaxf(mx, __shfl_xor(mx, 32));
  if (g == 0) red[wm][ln][wq] = mx;
  __syncthreads();
  mx = fmaxf(fmaxf(red[wm][ln][0], red[wm][ln][1]),
             fmaxf(red[wm][ln][2], red[wm][ln][3]));

  float sum = 0.f;
#pragma unroll
  for (int tt = 0; tt < 16; ++tt)
#pragma unroll
    for (int r = 0; r < 4; ++r) {
      float p = exp2f((sc[tt][r] - mx) * 1.4426950408889634f);
      sc[tt][r] = p;
      sum += p;
    }
  sum += __shfl_xor(sum, 16);
  sum += __shfl_xor(sum, 32);
  __syncthreads();                    // all red(max) reads done
  if (g == 0) red[wm][ln][wq] = sum;
  __syncthreads();
  float l4 = red[wm][ln][0] + red[wm][ln][1] +
             red[wm][ln][2] + red[wm][ln][3];
  float rinv = 1.0f / l4;
#pragma unroll
  for (int tt = 0; tt < 16; ++tt)
#pragma unroll
    for (int r = 0; r < 4; ++r) sc[tt][r] *= rinv;

  // ---- build bf16 PV A-fragments (frees sc after attn write) ----
  bf16x8 af8[8];
#pragma unroll
  for (int c = 0; c < 8; ++c) {
    bf16x8 a;
#pragma unroll
    for (int r = 0; r < 4; ++r) a[r]     = (short)f2bf(sc[2 * c][r]);
#pragma unroll
    for (int r = 0; r < 4; ++r) a[4 + r] = (short)f2bf(sc[2 * c + 1][r]);
    af8[c] = a;
  }

  // ---- write normalized attention via per-wave dbuf transpose tiles ----
  {
    const int mr = lane >> 2, ns = (lane & 3) * 4;
    const size_t abase = ((size_t)(b * 16 + h) * 1024 + (m0 + wm * 16));
#pragma unroll
    for (int tt = 0; tt < 16; ++tt) {
      float* T = &sm.Tb[wv][tt & 1][0][0];       // [16][20]
      *(f32x4*)&T[ln * 20 + g * 4] = sc[tt];     // wave-internal, in-order DS
      f32x4 vv = *(const f32x4*)&T[mr * 20 + ns];
      *(f32x4*)(attn_out + (abase + mr) * 1024 + tt * 64 + wq * 16 + ns) = vv;
    }
  }

  // ---- PV: direct-global V^T fragments, depth-2 static pipeline ----
  f32x4 cacc[4];
#pragma unroll
  for (int i = 0; i < 4; ++i) cacc[i] = {0.f, 0.f, 0.f, 0.f};
  {
    const unsigned short* vb =
        vt + ((size_t)(b * 16 + h) * 64 + ln) * 1024 + wq * 16 + g * 4;
    bf16x4 va[2][4], vc[2][4];
#pragma unroll
    for (int ni = 0; ni < 4; ++ni) {
      va[0][ni] = *(const bf16x4*)(vb + ni * 16384);
      vc[0][ni] = *(const bf16x4*)(vb + ni * 16384 + 64);
    }
#pragma unroll
    for (int c = 0; c < 8; ++c) {
      const int cur = c & 1, nxt = cur ^ 1;
      if (c < 7) {
#pragma unroll
        for (int ni = 0; ni < 4; ++ni) {
          va[nxt][ni] = *(const bf16x4*)(vb + ni * 16384 + (c + 1) * 128);
          vc[nxt][ni] = *(const bf16x4*)(vb + ni * 16384 + (c + 1) * 128 + 64);
        }
      }
#pragma unroll
      for (int ni = 0; ni < 4; ++ni) {
        bf16x8 bfr = { va[cur][ni][0], va[cur][ni][1], va[cur][ni][2], va[cur][ni][3],
                       vc[cur][ni][0], vc[cur][ni][1], vc[cur][ni][2], vc[cur][ni][3] };
        cacc[ni] = __builtin_amdgcn_mfma_f32_16x16x32_bf16(af8[c], bfr, cacc[ni], 0, 0, 0);
      }
    }
  }

  // ---- cross-wave ctx reduction + residual -> d_out ----
  __syncthreads();                    // Tb reads done everywhere; reuse as ctxp
#pragma unroll
  for (int ni = 0; ni < 4; ++ni)
#pragma unroll
    for (int r = 0; r < 4; ++r)
      sm.ctxp[wq][wm * 16 + g * 4 + r][ni * 16 + ln] = cacc[ni][r];
  __syncthreads();
  {
    const int m = t >> 4, d4 = (t & 15) * 4;
    f32x4 s0 = *(const f32x4*)&sm.ctxp[0][m][d4];
    f32x4 s1 = *(const f32x4*)&sm.ctxp[1][m][d4];
    f32x4 s2 = *(const f32x4*)&sm.ctxp[2][m][d4];
    f32x4 s3 = *(const f32x4*)&sm.ctxp[3][m][d4];
    f32x4 s = s0 + s1 + s2 + s3;
    const unsigned short* qrow = qp + (rowbase + m) * 1024 + h * 64 + d4;
    u16x4 qv = *(const u16x4*)qrow;
    f32x4 qf32 = { bf2f(qv[0]), bf2f(qv[1]), bf2f(qv[2]), bf2f(qv[3]) };
    s = s + qf32;
    *(f32x4*)(res_out + (rowbase + m) * 1024 + h * 64 + d4) = s;
  }
}

// ---------------------------------------------------------------------------
// In-place LayerNorm on d_out[:B*L*D]: out = LN(out) * g + b, one block/row.
// ---------------------------------------------------------------------------
__global__ __launch_bounds__(256) void ln_kernel(
    float* __restrict__ io,
    const float* __restrict__ gma, const float* __restrict__ bta)
{
  __shared__ float rbuf[2][4];
  const int r = blockIdx.x, t = threadIdx.x;
  const int i4 = t * 4;
  const size_t base = (size_t)r * 1024 + i4;
  f32x4 x = *(const f32x4*)(io + base);
  float s = x[0] + x[1] + x[2] + x[3];
  float q = x[0]*x[0] + x[1]*x[1] + x[2]*x[2] + x[3]*x[3];
#pragma unroll
  for (int off = 1; off < 64; off <<= 1) {
    s += __shfl_xor(s, off);
    q += __shfl_xor(q, off);
  }
  const int wv = t >> 6;
  if ((t & 63) == 0) { rbuf[0][wv] = s; rbuf[1][wv] = q; }
  __syncthreads();
  s = rbuf[0][0] + rbuf[0][1] + rbuf[0][2] + rbuf[0][3];
  q = rbuf[1][0] + rbuf[1][1] + rbuf[1][2] + rbuf[1][3];
  float mu = s * (1.0f / 1024.0f);
  float var = q * (1.0f / 1024.0f) - mu * mu;
  float is = rsqrtf(var + 1e-6f);
  f32x4 gv = *(const f32x4*)(gma + i4);
  f32x4 bv = *(const f32x4*)(bta + i4);
  f32x4 o;
#pragma unroll
  for (int k = 0; k < 4; ++k) o[k] = (x[k] - mu) * is * gv[k] + bv[k];
  *(f32x4*)(io + base) = o;
}

// ---------------------------------------------------------------------------
extern "C" void kernel_launch(void* const* d_in, const int* in_sizes, int n_in,
                              void* d_out, int out_size, void* d_ws, size_t ws_size,
                              hipStream_t stream) {
  const float* q  = (const float*)d_in[0];
  const float* k  = (const float*)d_in[1];
  const float* v  = (const float*)d_in[2];
  const unsigned char* masks = (const unsigned char*)d_in[3];
  const float* Wq = (const float*)d_in[4];
  const float* bq = (const float*)d_in[5];
  const float* Wk = (const float*)d_in[6];
  const float* bk = (const float*)d_in[7];
  const float* Wv = (const float*)d_in[8];
  const float* bv = (const float*)d_in[9];
  const float* lg = (const float*)d_in[10];
  const float* lb = (const float*)d_in[11];

  float* out = (float*)d_out;
  float* attn_out = out + (size_t)4 * 1024 * 1024;

  // bf16 input scratch lives in the attn region of d_out (overwritten later
  // by attn_kernel -- all reads happen in cvt/gemm, stream-ordered before).
  unsigned short* xq  = (unsigned short*)attn_out;
  unsigned short* xk  = xq + 4194304;
  unsigned short* xv  = xk + 4194304;
  unsigned short* wqb = xv + 4194304;
  unsigned short* wkb = wqb + 1048576;
  unsigned short* wvb = wkb + 1048576;

  // workspace: 24 MB (qp | kp | vt, all bf16 4M elems each)
  unsigned short* qp = (unsigned short*)d_ws;
  unsigned short* kp = qp + 4194304;
  unsigned short* vt = kp + 4194304;

  hipLaunchKernelGGL(cvt_kernel, dim3(7680), dim3(256), 0, stream,
                     q, k, v, Wq, Wk, Wv, xq, xk, xv, wqb, wkb, wvb);
  hipLaunchKernelGGL(gemm_kernel, dim3(768), dim3(512), 0, stream,
                     xq, xk, xv, wqb, wkb, wvb, bq, bk, bv, qp, kp, vt);
  hipLaunchKernelGGL(attn_kernel, dim3(2048), dim3(512), 0, stream,
                     qp, kp, vt, masks, attn_out, out);
  hipLaunchKernelGGL(ln_kernel, dim3(4096), dim3(256), 0, stream,
                     out, lg, lb);
}

// Round 5
// 280.498 us; speedup vs baseline: 1.5566x; 1.0974x over previous
//
#include <hip/hip_runtime.h>
#include <hip/hip_bf16.h>

typedef short bf16x8 __attribute__((ext_vector_type(8)));
typedef short bf16x4 __attribute__((ext_vector_type(4)));
typedef float f32x4 __attribute__((ext_vector_type(4)));
typedef unsigned short u16x8 __attribute__((ext_vector_type(8)));
typedef unsigned short u16x4 __attribute__((ext_vector_type(4)));

#define DEV static __device__ __forceinline__

DEV unsigned short f2bf(float f) {
  unsigned int u = __builtin_bit_cast(unsigned int, f);
  u += 0x7FFFu + ((u >> 16) & 1u);   // round-to-nearest-even
  return (unsigned short)(u >> 16);
}
DEV float bf2f(unsigned short u) {
  return __builtin_bit_cast(float, (unsigned int)u << 16);
}

DEV void gload_lds16(const unsigned short* g, unsigned short* l) {
  __builtin_amdgcn_global_load_lds(
      (const __attribute__((address_space(1))) unsigned int*)g,
      (__attribute__((address_space(3))) unsigned int*)l, 16, 0, 0);
}

DEV void waitv(int n) {   // n is compile-time under full unroll -> folds
  switch (n) {
    case 0: asm volatile("s_waitcnt vmcnt(0)" ::: "memory"); break;
    case 1: asm volatile("s_waitcnt vmcnt(1)" ::: "memory"); break;
    case 2: asm volatile("s_waitcnt vmcnt(2)" ::: "memory"); break;
    case 4: asm volatile("s_waitcnt vmcnt(4)" ::: "memory"); break;
    default: asm volatile("s_waitcnt vmcnt(0)" ::: "memory"); break;
  }
}

#define BAR() do { __builtin_amdgcn_s_barrier(); __builtin_amdgcn_sched_barrier(0); } while (0)
#define LBAR() do { asm volatile("s_waitcnt lgkmcnt(0)" ::: "memory"); \
                    __builtin_amdgcn_sched_barrier(0); \
                    __builtin_amdgcn_s_barrier(); \
                    __builtin_amdgcn_sched_barrier(0); } while (0)

// ---------------------------------------------------------------------------
// Convert pass: f32 -> bf16 for q,k,v (4M elems each) and Wq,Wk,Wv (1M each).
// ---------------------------------------------------------------------------
__global__ __launch_bounds__(256) void cvt_kernel(
    const float* __restrict__ q, const float* __restrict__ k,
    const float* __restrict__ v, const float* __restrict__ wq,
    const float* __restrict__ wk, const float* __restrict__ wv,
    unsigned short* __restrict__ xq, unsigned short* __restrict__ xk,
    unsigned short* __restrict__ xv, unsigned short* __restrict__ wqb,
    unsigned short* __restrict__ wkb, unsigned short* __restrict__ wvb)
{
  int tid = blockIdx.x * 256 + threadIdx.x;
  const float* src; unsigned short* dst; int off;
  if      (tid <  524288) { src = q;  dst = xq;  off = tid; }
  else if (tid < 1048576) { src = k;  dst = xk;  off = tid -  524288; }
  else if (tid < 1572864) { src = v;  dst = xv;  off = tid - 1048576; }
  else if (tid < 1703936) { src = wq; dst = wqb; off = tid - 1572864; }
  else if (tid < 1835008) { src = wk; dst = wkb; off = tid - 1703936; }
  else                    { src = wv; dst = wvb; off = tid - 1835008; }
  size_t e = (size_t)off * 8;
  float4 a = *(const float4*)(src + e);
  float4 b = *(const float4*)(src + e + 4);
  u16x8 p = { f2bf(a.x), f2bf(a.y), f2bf(a.z), f2bf(a.w),
              f2bf(b.x), f2bf(b.y), f2bf(b.z), f2bf(b.w) };
  *(u16x8*)(dst + e) = p;
}

// ---------------------------------------------------------------------------
// Fused projection GEMMs (unchanged from r4): seg picks (X,W,bias,out,mode).
// ---------------------------------------------------------------------------
__global__ __launch_bounds__(512) void gemm_kernel(
    const unsigned short* __restrict__ xq, const unsigned short* __restrict__ xk,
    const unsigned short* __restrict__ xv, const unsigned short* __restrict__ wqb,
    const unsigned short* __restrict__ wkb, const unsigned short* __restrict__ wvb,
    const float* __restrict__ bq, const float* __restrict__ bk,
    const float* __restrict__ bv, unsigned short* __restrict__ qp,
    unsigned short* __restrict__ kp, unsigned short* __restrict__ vt)
{
  __shared__ union {
    struct { unsigned short A[128][64]; unsigned short B[128][64]; } ab;
    unsigned short T[128][128];
  } smu;
  const int t = threadIdx.x, lane = t & 63, wv8 = t >> 6;
  const int ln = lane & 15, g = lane >> 4;
  const int wm2 = wv8 >> 2, wn4 = wv8 & 3;
  const int seg = blockIdx.x >> 8, lb = blockIdx.x & 255;
  const int n0 = (lb & 7) * 128, m0 = (lb >> 3) * 128;

  const unsigned short* X; const unsigned short* W; const float* bias;
  unsigned short* outR; int mode;
  if (seg == 0)      { X = xq; W = wqb; bias = bq; outR = qp; mode = 0; }
  else if (seg == 1) { X = xk; W = wkb; bias = bk; outR = kp; mode = 0; }
  else               { X = xv; W = wvb; bias = bv; outR = vt; mode = 2; }

  f32x4 acc[4][2];
#pragma unroll
  for (int i = 0; i < 4; ++i)
#pragma unroll
    for (int j = 0; j < 2; ++j) acc[i][j] = {0.f, 0.f, 0.f, 0.f};

  const int lrow = lane >> 3, lcol = (lane & 7) * 8;
  for (int kt = 0; kt < 16; ++kt) {
    const int k0 = kt * 64;
    __syncthreads();
#pragma unroll
    for (int i = 0; i < 2; ++i) {
      const int r = wv8 * 16 + i * 8;
      gload_lds16(X + (size_t)(m0 + r + lrow) * 1024 + k0 + lcol, &smu.ab.A[r][0]);
      gload_lds16(W + (size_t)(n0 + r + lrow) * 1024 + k0 + lcol, &smu.ab.B[r][0]);
    }
    __syncthreads();
#pragma unroll
    for (int ks = 0; ks < 2; ++ks) {
      bf16x8 af[4], bfr[2];
#pragma unroll
      for (int i = 0; i < 4; ++i)
        af[i] = *(const bf16x8*)&smu.ab.A[wm2 * 64 + i * 16 + ln][ks * 32 + g * 8];
#pragma unroll
      for (int j = 0; j < 2; ++j)
        bfr[j] = *(const bf16x8*)&smu.ab.B[wn4 * 32 + j * 16 + ln][ks * 32 + g * 8];
#pragma unroll
      for (int i = 0; i < 4; ++i)
#pragma unroll
        for (int j = 0; j < 2; ++j)
          acc[i][j] = __builtin_amdgcn_mfma_f32_16x16x32_bf16(
              af[i], bfr[j], acc[i][j], 0, 0, 0);
    }
  }

  float bvv[2];
#pragma unroll
  for (int j = 0; j < 2; ++j) bvv[j] = bias[n0 + wn4 * 32 + j * 16 + ln];

  if (mode == 0) {
#pragma unroll
    for (int i = 0; i < 4; ++i)
#pragma unroll
      for (int j = 0; j < 2; ++j)
#pragma unroll
        for (int r = 0; r < 4; ++r) {
          int row = m0 + wm2 * 64 + i * 16 + g * 4 + r;
          int col = n0 + wn4 * 32 + j * 16 + ln;
          outR[(size_t)row * 1024 + col] = f2bf(acc[i][j][r] + bvv[j]);
        }
  } else {
    __syncthreads();
#pragma unroll
    for (int i = 0; i < 4; ++i)
#pragma unroll
      for (int j = 0; j < 2; ++j)
#pragma unroll
        for (int r = 0; r < 4; ++r)
          smu.T[wn4 * 32 + j * 16 + ln][wm2 * 64 + i * 16 + g * 4 + r] =
              f2bf(acc[i][j][r] + bvv[j]);
    __syncthreads();
    const int bb = m0 >> 10, l0 = m0 & 1023;
#pragma unroll
    for (int it = 0; it < 4; ++it) {
      const int col = it * 32 + (t >> 4);
      const int r8 = (t & 15) * 8;
      *(u16x8*)&outR[((size_t)(bb * 16 + (n0 >> 6) + (col >> 6)) * 64 + (col & 63)) * 1024 + l0 + r8] =
          *(const u16x8*)&smu.T[col][r8];
    }
  }
}

// ---------------------------------------------------------------------------
// Attention: block = (b, h, 32 q-rows), 512 threads = 8 waves (4 wq x 2 wm).
// S^T = K*Q^T (validated mapping). K and V^T streamed through LDS with
// global_load_lds DMA: 4-slot ring, counted vmcnt (3 chunks in flight),
// 1 raw s_barrier/chunk, both-sides XOR swizzle (linear DMA dest,
// pre-swizzled source unit, swizzled ds_read). Attention stored directly
// from bf16 PV A-fragments (nontemporal). Residual qp+ctx -> d_out.
// ---------------------------------------------------------------------------
__global__ __launch_bounds__(512, 2) void attn_kernel(
    const unsigned short* __restrict__ qp, const unsigned short* __restrict__ kp,
    const unsigned short* __restrict__ vt, const unsigned char* __restrict__ masks,
    float* __restrict__ attn_out, float* __restrict__ res_out)
{
  __shared__ union {
    unsigned short Kb[4][64][64];    // QK phase: 4 x 8KB chunk slots
    unsigned short Vb[4][64][128];   // PV phase: 4 x 16KB chunk slots
    float ctxp[4][32][64];           // reduction phase
  } sm;
  __shared__ float red[2][16][4];

  const int t = threadIdx.x;
  const int wv = t >> 6, lane = t & 63;
  const int ln = lane & 15, g = lane >> 4;
  const int wq = wv & 3, wm = wv >> 2;
  const int hw = blockIdx.x;
  const int lid = (hw & 7) * 256 + (hw >> 3);  // cluster same-(b,h) per XCD
  const int b = lid >> 9, h = (lid >> 5) & 15, m0 = (lid & 31) * 32;
  const size_t rowbase = (size_t)(b * 1024 + m0);

  // ---- Q fragments: direct global, drain before DMA pipelines start ----
  bf16x8 qf[2];
  {
    const unsigned short* qb =
        qp + (rowbase + wm * 16 + ln) * 1024 + h * 64 + g * 8;
    qf[0] = *(const bf16x8*)qb;
    qf[1] = *(const bf16x8*)(qb + 32);
  }
  asm volatile("s_waitcnt vmcnt(0)" ::: "memory");

  // staging geometry
  const int slr = lane >> 3;                 // 0..7 local row (K chunks)
  const int suK = (lane & 7) ^ slr;          // swizzled K source unit
  const int vlr = lane >> 4;                 // 0..3 local row (V chunks)
  const int vu1 = (lane & 15) ^ vlr;         // V source units (rows +0..3)
  const int vu2 = (lane & 15) ^ (4 + vlr);   //               (rows +4..7)
  const unsigned short* kbase = kp + (size_t)b * 1048576 + h * 64;
  const unsigned short* vtb = vt + ((size_t)(b * 16 + h) * 64) * 1024;

#define STAGE_K(tt) gload_lds16( \
    kbase + (size_t)((tt) * 64 + wv * 8 + slr) * 1024 + suK * 8, \
    &sm.Kb[(tt) & 3][wv * 8][0])
#define STAGE_V(c) do { \
    gload_lds16(vtb + (size_t)(wv * 8 + vlr) * 1024 + (c) * 128 + vu1 * 8, \
                &sm.Vb[(c) & 3][wv * 8][0]); \
    gload_lds16(vtb + (size_t)(wv * 8 + 4 + vlr) * 1024 + (c) * 128 + vu2 * 8, \
                &sm.Vb[(c) & 3][wv * 8 + 4][0]); } while (0)

  f32x4 sc[16];
#pragma unroll
  for (int i = 0; i < 16; ++i) sc[i] = {0.f, 0.f, 0.f, 0.f};

  // ---- QK^T: DMA ring, counted vmcnt, 1 barrier/chunk ----
  STAGE_K(0); STAGE_K(1); STAGE_K(2);
  const int rr = wq * 16 + ln;
#pragma unroll
  for (int tt = 0; tt < 16; ++tt) {
    waitv(tt <= 13 ? 2 : (tt == 14 ? 1 : 0));
    BAR();
    if (tt + 3 < 16) STAGE_K(tt + 3);
    bf16x8 kf0 = *(const bf16x8*)&sm.Kb[tt & 3][rr][((g) ^ (ln & 7)) * 8];
    bf16x8 kf1 = *(const bf16x8*)&sm.Kb[tt & 3][rr][((4 + g) ^ (ln & 7)) * 8];
    sc[tt] = __builtin_amdgcn_mfma_f32_16x16x32_bf16(kf0, qf[0], sc[tt], 0, 0, 0);
    sc[tt] = __builtin_amdgcn_mfma_f32_16x16x32_bf16(kf1, qf[1], sc[tt], 0, 0, 0);
  }

  // ---- mask loads (issued before V stages: consuming them won't drain V) ----
  unsigned mw[16];
  {
    const unsigned char* mrow =
        masks + ((size_t)b * 1024 + m0 + wm * 16 + ln) * 1024 + wq * 16 + g * 4;
#pragma unroll
    for (int tt = 0; tt < 16; ++tt) mw[tt] = *(const unsigned*)(mrow + tt * 64);
  }

  LBAR();                       // all QK reads done; Kb region reusable
  STAGE_V(0); STAGE_V(1); STAGE_V(2);   // V latency hides under softmax

  // ---- softmax (rows lane-local: q-row = ln) ----
  float mx = -3.0e30f;
#pragma unroll
  for (int tt = 0; tt < 16; ++tt) {
#pragma unroll
    for (int r = 0; r < 4; ++r) sc[tt][r] *= 0.125f;   // 1/sqrt(64)
    if (mw[tt]) {
#pragma unroll
      for (int r = 0; r < 4; ++r)
        if ((mw[tt] >> (8 * r)) & 0xffu) sc[tt][r] = -1.0e30f;
    }
#pragma unroll
    for (int r = 0; r < 4; ++r) mx = fmaxf(mx, sc[tt][r]);
  }
  mx = fmaxf(mx, __shfl_xor(mx, 16));
  mx = fmaxf(mx, __shfl_xor(mx, 32));
  if (g == 0) red[wm][ln][wq] = mx;
  LBAR();
  mx = fmaxf(fmaxf(red[wm][ln][0], red[wm][ln][1]),
             fmaxf(red[wm][ln][2], red[wm][ln][3]));

  float sum = 0.f;
#pragma unroll
  for (int tt = 0; tt < 16; ++tt)
#pragma unroll
    for (int r = 0; r < 4; ++r) {
      float p = exp2f((sc[tt][r] - mx) * 1.4426950408889634f);
      sc[tt][r] = p;
      sum += p;
    }
  sum += __shfl_xor(sum, 16);
  sum += __shfl_xor(sum, 32);
  LBAR();                       // all red(max) reads done
  if (g == 0) red[wm][ln][wq] = sum;
  LBAR();
  float l4 = red[wm][ln][0] + red[wm][ln][1] +
             red[wm][ln][2] + red[wm][ln][3];
  float rinv = 1.0f / l4;

  // ---- normalized bf16 P fragments (also the attention output values) ----
  bf16x8 af8[8];
#pragma unroll
  for (int c = 0; c < 8; ++c) {
    bf16x8 a;
#pragma unroll
    for (int r = 0; r < 4; ++r) a[r]     = (short)f2bf(sc[2 * c][r] * rinv);
#pragma unroll
    for (int r = 0; r < 4; ++r) a[4 + r] = (short)f2bf(sc[2 * c + 1][r] * rinv);
    af8[c] = a;
  }

  // ---- PV: DMA ring over V^T k-chunks of 128, counted vmcnt ----
  f32x4 cacc[4];
#pragma unroll
  for (int i = 0; i < 4; ++i) cacc[i] = {0.f, 0.f, 0.f, 0.f};
#pragma unroll
  for (int c = 0; c < 8; ++c) {
    waitv(c <= 5 ? 4 : (c == 6 ? 2 : 0));
    BAR();
    if (c + 3 < 8) STAGE_V(c + 3);
#pragma unroll
    for (int ni = 0; ni < 4; ++ni) {
      const int d = ni * 16 + ln;
      const int u0 = (2 * wq + (g >> 1)) ^ (ln & 7);
      const int u1 = (8 + 2 * wq + (g >> 1)) ^ (ln & 7);
      bf16x4 b0 = *(const bf16x4*)&sm.Vb[c & 3][d][u0 * 8 + (g & 1) * 4];
      bf16x4 b1 = *(const bf16x4*)&sm.Vb[c & 3][d][u1 * 8 + (g & 1) * 4];
      bf16x8 bfr = { b0[0], b0[1], b0[2], b0[3], b1[0], b1[1], b1[2], b1[3] };
      cacc[ni] = __builtin_amdgcn_mfma_f32_16x16x32_bf16(af8[c], bfr, cacc[ni], 0, 0, 0);
    }
  }

  // ---- cross-wave ctx reduction + residual -> d_out ----
  LBAR();                       // all Vb reads done; reuse as ctxp
#pragma unroll
  for (int ni = 0; ni < 4; ++ni)
#pragma unroll
    for (int r = 0; r < 4; ++r)
      sm.ctxp[wq][wm * 16 + g * 4 + r][ni * 16 + ln] = cacc[ni][r];
  LBAR();
  {
    const int m = t >> 4, d4 = (t & 15) * 4;
    f32x4 s0 = *(const f32x4*)&sm.ctxp[0][m][d4];
    f32x4 s1 = *(const f32x4*)&sm.ctxp[1][m][d4];
    f32x4 s2 = *(const f32x4*)&sm.ctxp[2][m][d4];
    f32x4 s3 = *(const f32x4*)&sm.ctxp[3][m][d4];
    f32x4 s = s0 + s1 + s2 + s3;
    const unsigned short* qrow = qp + (rowbase + m) * 1024 + h * 64 + d4;
    u16x4 qv = *(const u16x4*)qrow;
    f32x4 qf32 = { bf2f(qv[0]), bf2f(qv[1]), bf2f(qv[2]), bf2f(qv[3]) };
    s = s + qf32;
    *(f32x4*)(res_out + (rowbase + m) * 1024 + h * 64 + d4) = s;
  }

  // ---- attention output: direct nontemporal stores from af8 ----
  {
    const size_t abase =
        ((size_t)(b * 16 + h) * 1024 + (m0 + wm * 16 + ln)) * 1024 + wq * 16 + g * 4;
#pragma unroll
    for (int c = 0; c < 8; ++c)
#pragma unroll
      for (int hf = 0; hf < 2; ++hf) {
        f32x4 v = { bf2f((unsigned short)af8[c][hf * 4 + 0]),
                    bf2f((unsigned short)af8[c][hf * 4 + 1]),
                    bf2f((unsigned short)af8[c][hf * 4 + 2]),
                    bf2f((unsigned short)af8[c][hf * 4 + 3]) };
        __builtin_nontemporal_store(v, (f32x4*)(attn_out + abase + (2 * c + hf) * 64));
      }
  }
#undef STAGE_K
#undef STAGE_V
}

// ---------------------------------------------------------------------------
// In-place LayerNorm on d_out[:B*L*D]: out = LN(out) * g + b, one block/row.
// ---------------------------------------------------------------------------
__global__ __launch_bounds__(256) void ln_kernel(
    float* __restrict__ io,
    const float* __restrict__ gma, const float* __restrict__ bta)
{
  __shared__ float rbuf[2][4];
  const int r = blockIdx.x, t = threadIdx.x;
  const int i4 = t * 4;
  const size_t base = (size_t)r * 1024 + i4;
  f32x4 x = *(const f32x4*)(io + base);
  float s = x[0] + x[1] + x[2] + x[3];
  float q = x[0]*x[0] + x[1]*x[1] + x[2]*x[2] + x[3]*x[3];
#pragma unroll
  for (int off = 1; off < 64; off <<= 1) {
    s += __shfl_xor(s, off);
    q += __shfl_xor(q, off);
  }
  const int wv = t >> 6;
  if ((t & 63) == 0) { rbuf[0][wv] = s; rbuf[1][wv] = q; }
  __syncthreads();
  s = rbuf[0][0] + rbuf[0][1] + rbuf[0][2] + rbuf[0][3];
  q = rbuf[1][0] + rbuf[1][1] + rbuf[1][2] + rbuf[1][3];
  float mu = s * (1.0f / 1024.0f);
  float var = q * (1.0f / 1024.0f) - mu * mu;
  float is = rsqrtf(var + 1e-6f);
  f32x4 gv = *(const f32x4*)(gma + i4);
  f32x4 bv = *(const f32x4*)(bta + i4);
  f32x4 o;
#pragma unroll
  for (int k = 0; k < 4; ++k) o[k] = (x[k] - mu) * is * gv[k] + bv[k];
  *(f32x4*)(io + base) = o;
}

// ---------------------------------------------------------------------------
extern "C" void kernel_launch(void* const* d_in, const int* in_sizes, int n_in,
                              void* d_out, int out_size, void* d_ws, size_t ws_size,
                              hipStream_t stream) {
  const float* q  = (const float*)d_in[0];
  const float* k  = (const float*)d_in[1];
  const float* v  = (const float*)d_in[2];
  const unsigned char* masks = (const unsigned char*)d_in[3];
  const float* Wq = (const float*)d_in[4];
  const float* bq = (const float*)d_in[5];
  const float* Wk = (const float*)d_in[6];
  const float* bk = (const float*)d_in[7];
  const float* Wv = (const float*)d_in[8];
  const float* bv = (const float*)d_in[9];
  const float* lg = (const float*)d_in[10];
  const float* lb = (const float*)d_in[11];

  float* out = (float*)d_out;
  float* attn_out = out + (size_t)4 * 1024 * 1024;

  // bf16 input scratch lives in the attn region of d_out (overwritten later
  // by attn_kernel -- all reads happen in cvt/gemm, stream-ordered before).
  unsigned short* xq  = (unsigned short*)attn_out;
  unsigned short* xk  = xq + 4194304;
  unsigned short* xv  = xk + 4194304;
  unsigned short* wqb = xv + 4194304;
  unsigned short* wkb = wqb + 1048576;
  unsigned short* wvb = wkb + 1048576;

  // workspace: 24 MB (qp | kp | vt, all bf16 4M elems each)
  unsigned short* qp = (unsigned short*)d_ws;
  unsigned short* kp = qp + 4194304;
  unsigned short* vt = kp + 4194304;

  hipLaunchKernelGGL(cvt_kernel, dim3(7680), dim3(256), 0, stream,
                     q, k, v, Wq, Wk, Wv, xq, xk, xv, wqb, wkb, wvb);
  hipLaunchKernelGGL(gemm_kernel, dim3(768), dim3(512), 0, stream,
                     xq, xk, xv, wqb, wkb, wvb, bq, bk, bv, qp, kp, vt);
  hipLaunchKernelGGL(attn_kernel, dim3(2048), dim3(512), 0, stream,
                     qp, kp, vt, masks, attn_out, out);
  hipLaunchKernelGGL(ln_kernel, dim3(4096), dim3(256), 0, stream,
                     out, lg, lb);
}

// Round 6
// 266.618 us; speedup vs baseline: 1.6376x; 1.0521x over previous
//
#include <hip/hip_runtime.h>
#include <hip/hip_bf16.h>

typedef short bf16x8 __attribute__((ext_vector_type(8)));
typedef short bf16x4 __attribute__((ext_vector_type(4)));
typedef float f32x4 __attribute__((ext_vector_type(4)));
typedef unsigned short u16x8 __attribute__((ext_vector_type(8)));
typedef unsigned short u16x4 __attribute__((ext_vector_type(4)));

#define DEV static __device__ __forceinline__

DEV unsigned short f2bf(float f) {
  unsigned int u = __builtin_bit_cast(unsigned int, f);
  u += 0x7FFFu + ((u >> 16) & 1u);   // round-to-nearest-even
  return (unsigned short)(u >> 16);
}
DEV float bf2f(unsigned short u) {
  return __builtin_bit_cast(float, (unsigned int)u << 16);
}

DEV void gload_lds16(const unsigned short* g, unsigned short* l) {
  __builtin_amdgcn_global_load_lds(
      (const __attribute__((address_space(1))) unsigned int*)g,
      (__attribute__((address_space(3))) unsigned int*)l, 16, 0, 0);
}

DEV void waitv(int n) {   // n is compile-time under full unroll -> folds
  switch (n) {
    case 0: asm volatile("s_waitcnt vmcnt(0)" ::: "memory"); break;
    case 1: asm volatile("s_waitcnt vmcnt(1)" ::: "memory"); break;
    case 2: asm volatile("s_waitcnt vmcnt(2)" ::: "memory"); break;
    case 4: asm volatile("s_waitcnt vmcnt(4)" ::: "memory"); break;
    default: asm volatile("s_waitcnt vmcnt(0)" ::: "memory"); break;
  }
}

#define BAR() do { __builtin_amdgcn_s_barrier(); __builtin_amdgcn_sched_barrier(0); } while (0)
#define LBAR() do { asm volatile("s_waitcnt lgkmcnt(0)" ::: "memory"); \
                    __builtin_amdgcn_sched_barrier(0); \
                    __builtin_amdgcn_s_barrier(); \
                    __builtin_amdgcn_sched_barrier(0); } while (0)

// ---------------------------------------------------------------------------
// Convert pass: f32 -> bf16 for q,k,v (4M elems each) and Wq,Wk,Wv (1M each).
// ---------------------------------------------------------------------------
__global__ __launch_bounds__(256) void cvt_kernel(
    const float* __restrict__ q, const float* __restrict__ k,
    const float* __restrict__ v, const float* __restrict__ wq,
    const float* __restrict__ wk, const float* __restrict__ wv,
    unsigned short* __restrict__ xq, unsigned short* __restrict__ xk,
    unsigned short* __restrict__ xv, unsigned short* __restrict__ wqb,
    unsigned short* __restrict__ wkb, unsigned short* __restrict__ wvb)
{
  int tid = blockIdx.x * 256 + threadIdx.x;
  const float* src; unsigned short* dst; int off;
  if      (tid <  524288) { src = q;  dst = xq;  off = tid; }
  else if (tid < 1048576) { src = k;  dst = xk;  off = tid -  524288; }
  else if (tid < 1572864) { src = v;  dst = xv;  off = tid - 1048576; }
  else if (tid < 1703936) { src = wq; dst = wqb; off = tid - 1572864; }
  else if (tid < 1835008) { src = wk; dst = wkb; off = tid - 1703936; }
  else                    { src = wv; dst = wvb; off = tid - 1835008; }
  size_t e = (size_t)off * 8;
  float4 a = *(const float4*)(src + e);
  float4 b = *(const float4*)(src + e + 4);
  u16x8 p = { f2bf(a.x), f2bf(a.y), f2bf(a.z), f2bf(a.w),
              f2bf(b.x), f2bf(b.y), f2bf(b.z), f2bf(b.w) };
  *(u16x8*)(dst + e) = p;
}

// ---------------------------------------------------------------------------
// Fused projection GEMMs (unchanged): seg picks (X,W,bias,out,mode).
// ---------------------------------------------------------------------------
__global__ __launch_bounds__(512) void gemm_kernel(
    const unsigned short* __restrict__ xq, const unsigned short* __restrict__ xk,
    const unsigned short* __restrict__ xv, const unsigned short* __restrict__ wqb,
    const unsigned short* __restrict__ wkb, const unsigned short* __restrict__ wvb,
    const float* __restrict__ bq, const float* __restrict__ bk,
    const float* __restrict__ bv, unsigned short* __restrict__ qp,
    unsigned short* __restrict__ kp, unsigned short* __restrict__ vt)
{
  __shared__ union {
    struct { unsigned short A[128][64]; unsigned short B[128][64]; } ab;
    unsigned short T[128][128];
  } smu;
  const int t = threadIdx.x, lane = t & 63, wv8 = t >> 6;
  const int ln = lane & 15, g = lane >> 4;
  const int wm2 = wv8 >> 2, wn4 = wv8 & 3;
  const int seg = blockIdx.x >> 8, lb = blockIdx.x & 255;
  const int n0 = (lb & 7) * 128, m0 = (lb >> 3) * 128;

  const unsigned short* X; const unsigned short* W; const float* bias;
  unsigned short* outR; int mode;
  if (seg == 0)      { X = xq; W = wqb; bias = bq; outR = qp; mode = 0; }
  else if (seg == 1) { X = xk; W = wkb; bias = bk; outR = kp; mode = 0; }
  else               { X = xv; W = wvb; bias = bv; outR = vt; mode = 2; }

  f32x4 acc[4][2];
#pragma unroll
  for (int i = 0; i < 4; ++i)
#pragma unroll
    for (int j = 0; j < 2; ++j) acc[i][j] = {0.f, 0.f, 0.f, 0.f};

  const int lrow = lane >> 3, lcol = (lane & 7) * 8;
  for (int kt = 0; kt < 16; ++kt) {
    const int k0 = kt * 64;
    __syncthreads();
#pragma unroll
    for (int i = 0; i < 2; ++i) {
      const int r = wv8 * 16 + i * 8;
      gload_lds16(X + (size_t)(m0 + r + lrow) * 1024 + k0 + lcol, &smu.ab.A[r][0]);
      gload_lds16(W + (size_t)(n0 + r + lrow) * 1024 + k0 + lcol, &smu.ab.B[r][0]);
    }
    __syncthreads();
#pragma unroll
    for (int ks = 0; ks < 2; ++ks) {
      bf16x8 af[4], bfr[2];
#pragma unroll
      for (int i = 0; i < 4; ++i)
        af[i] = *(const bf16x8*)&smu.ab.A[wm2 * 64 + i * 16 + ln][ks * 32 + g * 8];
#pragma unroll
      for (int j = 0; j < 2; ++j)
        bfr[j] = *(const bf16x8*)&smu.ab.B[wn4 * 32 + j * 16 + ln][ks * 32 + g * 8];
#pragma unroll
      for (int i = 0; i < 4; ++i)
#pragma unroll
        for (int j = 0; j < 2; ++j)
          acc[i][j] = __builtin_amdgcn_mfma_f32_16x16x32_bf16(
              af[i], bfr[j], acc[i][j], 0, 0, 0);
    }
  }

  float bvv[2];
#pragma unroll
  for (int j = 0; j < 2; ++j) bvv[j] = bias[n0 + wn4 * 32 + j * 16 + ln];

  if (mode == 0) {
#pragma unroll
    for (int i = 0; i < 4; ++i)
#pragma unroll
      for (int j = 0; j < 2; ++j)
#pragma unroll
        for (int r = 0; r < 4; ++r) {
          int row = m0 + wm2 * 64 + i * 16 + g * 4 + r;
          int col = n0 + wn4 * 32 + j * 16 + ln;
          outR[(size_t)row * 1024 + col] = f2bf(acc[i][j][r] + bvv[j]);
        }
  } else {
    __syncthreads();
#pragma unroll
    for (int i = 0; i < 4; ++i)
#pragma unroll
      for (int j = 0; j < 2; ++j)
#pragma unroll
        for (int r = 0; r < 4; ++r)
          smu.T[wn4 * 32 + j * 16 + ln][wm2 * 64 + i * 16 + g * 4 + r] =
              f2bf(acc[i][j][r] + bvv[j]);
    __syncthreads();
    const int bb = m0 >> 10, l0 = m0 & 1023;
#pragma unroll
    for (int it = 0; it < 4; ++it) {
      const int col = it * 32 + (t >> 4);
      const int r8 = (t & 15) * 8;
      *(u16x8*)&outR[((size_t)(bb * 16 + (n0 >> 6) + (col >> 6)) * 64 + (col & 63)) * 1024 + l0 + r8] =
          *(const u16x8*)&smu.T[col][r8];
    }
  }
}

// ---------------------------------------------------------------------------
// Attention: block = (b, h, 32 q-rows), 512 threads = 8 waves (4 wq x 2 wm).
// S^T = K*Q^T (validated mapping). K and V^T streamed through LDS with
// global_load_lds DMA: 128-key chunks, 3-slot x 16KB ring shared by both
// phases (union = 48KB -> 3 blocks/CU), counted vmcnt (2 chunks in flight),
// 1 raw s_barrier per chunk, 4 MFMAs per chunk. Both-sides XOR swizzle
// (linear DMA dest, pre-swizzled source unit, swizzled ds_read).
// Attention stored from bf16 PV A-fragments with CACHED stores (L2 merges
// the four wq-waves' 64B pieces into full lines). Residual qp+ctx -> d_out.
// ---------------------------------------------------------------------------
__global__ __launch_bounds__(512, 2) void attn_kernel(
    const unsigned short* __restrict__ qp, const unsigned short* __restrict__ kp,
    const unsigned short* __restrict__ vt, const unsigned char* __restrict__ masks,
    float* __restrict__ attn_out, float* __restrict__ res_out)
{
  __shared__ union {
    unsigned short Kb[3][128][64];   // QK phase: 3 x 16KB chunk slots
    unsigned short Vb[3][64][128];   // PV phase: 3 x 16KB chunk slots
    float ctxp[4][32][64];           // reduction phase
  } sm;
  __shared__ float red[2][16][4];

  const int t = threadIdx.x;
  const int wv = t >> 6, lane = t & 63;
  const int ln = lane & 15, g = lane >> 4;
  const int wq = wv & 3, wm = wv >> 2;
  const int hw = blockIdx.x;
  const int lid = (hw & 7) * 256 + (hw >> 3);  // cluster same-(b,h) per XCD
  const int b = lid >> 9, h = (lid >> 5) & 15, m0 = (lid & 31) * 32;
  const size_t rowbase = (size_t)(b * 1024 + m0);

  // ---- Q fragments: direct global, drain before DMA pipelines start ----
  bf16x8 qf[2];
  {
    const unsigned short* qb =
        qp + (rowbase + wm * 16 + ln) * 1024 + h * 64 + g * 8;
    qf[0] = *(const bf16x8*)qb;
    qf[1] = *(const bf16x8*)(qb + 32);
  }
  asm volatile("s_waitcnt vmcnt(0)" ::: "memory");

  // staging geometry
  const int slr = lane >> 3;                 // 0..7 local row (K chunks)
  const int suK = (lane & 7) ^ slr;          // swizzled K source unit
  const int vlr = lane >> 4;                 // 0..3 local row (V chunks)
  const int vu1 = (lane & 15) ^ vlr;         // V source units (rows +0..3)
  const int vu2 = (lane & 15) ^ (4 + vlr);   //               (rows +4..7)
  const unsigned short* kbase = kp + (size_t)b * 1048576 + h * 64;
  const unsigned short* vtb = vt + ((size_t)(b * 16 + h) * 64) * 1024;

#define STAGE_K(c) do { \
    gload_lds16(kbase + (size_t)((c) * 128 + wv * 16 + slr) * 1024 + suK * 8, \
                &sm.Kb[(c) % 3][wv * 16][0]); \
    gload_lds16(kbase + (size_t)((c) * 128 + wv * 16 + 8 + slr) * 1024 + suK * 8, \
                &sm.Kb[(c) % 3][wv * 16 + 8][0]); } while (0)
#define STAGE_V(c) do { \
    gload_lds16(vtb + (size_t)(wv * 8 + vlr) * 1024 + (c) * 128 + vu1 * 8, \
                &sm.Vb[(c) % 3][wv * 8][0]); \
    gload_lds16(vtb + (size_t)(wv * 8 + 4 + vlr) * 1024 + (c) * 128 + vu2 * 8, \
                &sm.Vb[(c) % 3][wv * 8 + 4][0]); } while (0)

  f32x4 sc[16];
#pragma unroll
  for (int i = 0; i < 16; ++i) sc[i] = {0.f, 0.f, 0.f, 0.f};

  // ---- QK^T: 8 chunks of 128 keys, 3-slot ring, counted vmcnt ----
  STAGE_K(0); STAGE_K(1);
#pragma unroll
  for (int c = 0; c < 8; ++c) {
    waitv(c <= 6 ? 2 : 0);
    BAR();
    if (c + 2 < 8) STAGE_K(c + 2);
#pragma unroll
    for (int h2 = 0; h2 < 2; ++h2) {
      const int tt = 2 * c + h2;
      const int rl = h2 * 64 + wq * 16 + ln;
      bf16x8 kf0 = *(const bf16x8*)&sm.Kb[c % 3][rl][(g ^ (ln & 7)) * 8];
      bf16x8 kf1 = *(const bf16x8*)&sm.Kb[c % 3][rl][((4 + g) ^ (ln & 7)) * 8];
      sc[tt] = __builtin_amdgcn_mfma_f32_16x16x32_bf16(kf0, qf[0], sc[tt], 0, 0, 0);
      sc[tt] = __builtin_amdgcn_mfma_f32_16x16x32_bf16(kf1, qf[1], sc[tt], 0, 0, 0);
    }
  }

  // ---- mask loads (older than V stages; compiler waits won't drain V) ----
  unsigned mw[16];
  {
    const unsigned char* mrow =
        masks + ((size_t)b * 1024 + m0 + wm * 16 + ln) * 1024 + wq * 16 + g * 4;
#pragma unroll
    for (int tt = 0; tt < 16; ++tt) mw[tt] = *(const unsigned*)(mrow + tt * 64);
  }

  LBAR();                       // all QK reads done; ring reusable for V
  STAGE_V(0); STAGE_V(1);       // V latency hides under softmax

  // ---- softmax (rows lane-local: q-row = ln) ----
  float mx = -3.0e30f;
#pragma unroll
  for (int tt = 0; tt < 16; ++tt) {
#pragma unroll
    for (int r = 0; r < 4; ++r) sc[tt][r] *= 0.125f;   // 1/sqrt(64)
    if (mw[tt]) {
#pragma unroll
      for (int r = 0; r < 4; ++r)
        if ((mw[tt] >> (8 * r)) & 0xffu) sc[tt][r] = -1.0e30f;
    }
#pragma unroll
    for (int r = 0; r < 4; ++r) mx = fmaxf(mx, sc[tt][r]);
  }
  mx = fmaxf(mx, __shfl_xor(mx, 16));
  mx = fmaxf(mx, __shfl_xor(mx, 32));
  if (g == 0) red[wm][ln][wq] = mx;
  LBAR();
  mx = fmaxf(fmaxf(red[wm][ln][0], red[wm][ln][1]),
             fmaxf(red[wm][ln][2], red[wm][ln][3]));

  float sum = 0.f;
#pragma unroll
  for (int tt = 0; tt < 16; ++tt)
#pragma unroll
    for (int r = 0; r < 4; ++r) {
      float p = exp2f((sc[tt][r] - mx) * 1.4426950408889634f);
      sc[tt][r] = p;
      sum += p;
    }
  sum += __shfl_xor(sum, 16);
  sum += __shfl_xor(sum, 32);
  LBAR();                       // all red(max) reads done
  if (g == 0) red[wm][ln][wq] = sum;
  LBAR();
  float l4 = red[wm][ln][0] + red[wm][ln][1] +
             red[wm][ln][2] + red[wm][ln][3];
  float rinv = 1.0f / l4;

  // ---- normalized bf16 P fragments (also the attention output values) ----
  bf16x8 af8[8];
#pragma unroll
  for (int c = 0; c < 8; ++c) {
    bf16x8 a;
#pragma unroll
    for (int r = 0; r < 4; ++r) a[r]     = (short)f2bf(sc[2 * c][r] * rinv);
#pragma unroll
    for (int r = 0; r < 4; ++r) a[4 + r] = (short)f2bf(sc[2 * c + 1][r] * rinv);
    af8[c] = a;
  }

  // ---- PV: 8 chunks of 128 keys, same 3-slot ring, counted vmcnt ----
  f32x4 cacc[4];
#pragma unroll
  for (int i = 0; i < 4; ++i) cacc[i] = {0.f, 0.f, 0.f, 0.f};
#pragma unroll
  for (int c = 0; c < 8; ++c) {
    waitv(c <= 6 ? 2 : 0);
    BAR();
    if (c + 2 < 8) STAGE_V(c + 2);
#pragma unroll
    for (int ni = 0; ni < 4; ++ni) {
      const int d = ni * 16 + ln;
      const int u0 = (2 * wq + (g >> 1)) ^ (ln & 7);
      const int u1 = (8 + 2 * wq + (g >> 1)) ^ (ln & 7);
      bf16x4 b0 = *(const bf16x4*)&sm.Vb[c % 3][d][u0 * 8 + (g & 1) * 4];
      bf16x4 b1 = *(const bf16x4*)&sm.Vb[c % 3][d][u1 * 8 + (g & 1) * 4];
      bf16x8 bfr = { b0[0], b0[1], b0[2], b0[3], b1[0], b1[1], b1[2], b1[3] };
      cacc[ni] = __builtin_amdgcn_mfma_f32_16x16x32_bf16(af8[c], bfr, cacc[ni], 0, 0, 0);
    }
  }

  // ---- attention output: cached stores from af8 (overlap with epilogue) ----
  {
    const size_t abase =
        ((size_t)(b * 16 + h) * 1024 + (m0 + wm * 16 + ln)) * 1024 + wq * 16 + g * 4;
#pragma unroll
    for (int c = 0; c < 8; ++c)
#pragma unroll
      for (int hf = 0; hf < 2; ++hf) {
        f32x4 v = { bf2f((unsigned short)af8[c][hf * 4 + 0]),
                    bf2f((unsigned short)af8[c][hf * 4 + 1]),
                    bf2f((unsigned short)af8[c][hf * 4 + 2]),
                    bf2f((unsigned short)af8[c][hf * 4 + 3]) };
        *(f32x4*)(attn_out + abase + (2 * c + hf) * 64) = v;
      }
  }

  // ---- cross-wave ctx reduction + residual -> d_out ----
  LBAR();                       // all Vb reads done; reuse as ctxp
#pragma unroll
  for (int ni = 0; ni < 4; ++ni)
#pragma unroll
    for (int r = 0; r < 4; ++r)
      sm.ctxp[wq][wm * 16 + g * 4 + r][ni * 16 + ln] = cacc[ni][r];
  LBAR();
  {
    const int m = t >> 4, d4 = (t & 15) * 4;
    f32x4 s0 = *(const f32x4*)&sm.ctxp[0][m][d4];
    f32x4 s1 = *(const f32x4*)&sm.ctxp[1][m][d4];
    f32x4 s2 = *(const f32x4*)&sm.ctxp[2][m][d4];
    f32x4 s3 = *(const f32x4*)&sm.ctxp[3][m][d4];
    f32x4 s = s0 + s1 + s2 + s3;
    const unsigned short* qrow = qp + (rowbase + m) * 1024 + h * 64 + d4;
    u16x4 qv = *(const u16x4*)qrow;
    f32x4 qf32 = { bf2f(qv[0]), bf2f(qv[1]), bf2f(qv[2]), bf2f(qv[3]) };
    s = s + qf32;
    *(f32x4*)(res_out + (rowbase + m) * 1024 + h * 64 + d4) = s;
  }
#undef STAGE_K
#undef STAGE_V
}

// ---------------------------------------------------------------------------
// In-place LayerNorm on d_out[:B*L*D]: out = LN(out) * g + b, one block/row.
// ---------------------------------------------------------------------------
__global__ __launch_bounds__(256) void ln_kernel(
    float* __restrict__ io,
    const float* __restrict__ gma, const float* __restrict__ bta)
{
  __shared__ float rbuf[2][4];
  const int r = blockIdx.x, t = threadIdx.x;
  const int i4 = t * 4;
  const size_t base = (size_t)r * 1024 + i4;
  f32x4 x = *(const f32x4*)(io + base);
  float s = x[0] + x[1] + x[2] + x[3];
  float q = x[0]*x[0] + x[1]*x[1] + x[2]*x[2] + x[3]*x[3];
#pragma unroll
  for (int off = 1; off < 64; off <<= 1) {
    s += __shfl_xor(s, off);
    q += __shfl_xor(q, off);
  }
  const int wv = t >> 6;
  if ((t & 63) == 0) { rbuf[0][wv] = s; rbuf[1][wv] = q; }
  __syncthreads();
  s = rbuf[0][0] + rbuf[0][1] + rbuf[0][2] + rbuf[0][3];
  q = rbuf[1][0] + rbuf[1][1] + rbuf[1][2] + rbuf[1][3];
  float mu = s * (1.0f / 1024.0f);
  float var = q * (1.0f / 1024.0f) - mu * mu;
  float is = rsqrtf(var + 1e-6f);
  f32x4 gv = *(const f32x4*)(gma + i4);
  f32x4 bv = *(const f32x4*)(bta + i4);
  f32x4 o;
#pragma unroll
  for (int k = 0; k < 4; ++k) o[k] = (x[k] - mu) * is * gv[k] + bv[k];
  *(f32x4*)(io + base) = o;
}

// ---------------------------------------------------------------------------
extern "C" void kernel_launch(void* const* d_in, const int* in_sizes, int n_in,
                              void* d_out, int out_size, void* d_ws, size_t ws_size,
                              hipStream_t stream) {
  const float* q  = (const float*)d_in[0];
  const float* k  = (const float*)d_in[1];
  const float* v  = (const float*)d_in[2];
  const unsigned char* masks = (const unsigned char*)d_in[3];
  const float* Wq = (const float*)d_in[4];
  const float* bq = (const float*)d_in[5];
  const float* Wk = (const float*)d_in[6];
  const float* bk = (const float*)d_in[7];
  const float* Wv = (const float*)d_in[8];
  const float* bv = (const float*)d_in[9];
  const float* lg = (const float*)d_in[10];
  const float* lb = (const float*)d_in[11];

  float* out = (float*)d_out;
  float* attn_out = out + (size_t)4 * 1024 * 1024;

  // bf16 input scratch lives in the attn region of d_out (overwritten later
  // by attn_kernel -- all reads happen in cvt/gemm, stream-ordered before).
  unsigned short* xq  = (unsigned short*)attn_out;
  unsigned short* xk  = xq + 4194304;
  unsigned short* xv  = xk + 4194304;
  unsigned short* wqb = xv + 4194304;
  unsigned short* wkb = wqb + 1048576;
  unsigned short* wvb = wkb + 1048576;

  // workspace: 24 MB (qp | kp | vt, all bf16 4M elems each)
  unsigned short* qp = (unsigned short*)d_ws;
  unsigned short* kp = qp + 4194304;
  unsigned short* vt = kp + 4194304;

  hipLaunchKernelGGL(cvt_kernel, dim3(7680), dim3(256), 0, stream,
                     q, k, v, Wq, Wk, Wv, xq, xk, xv, wqb, wkb, wvb);
  hipLaunchKernelGGL(gemm_kernel, dim3(768), dim3(512), 0, stream,
                     xq, xk, xv, wqb, wkb, wvb, bq, bk, bv, qp, kp, vt);
  hipLaunchKernelGGL(attn_kernel, dim3(2048), dim3(512), 0, stream,
                     qp, kp, vt, masks, attn_out, out);
  hipLaunchKernelGGL(ln_kernel, dim3(4096), dim3(256), 0, stream,
                     out, lg, lb);
}

// Round 7
// 193.935 us; speedup vs baseline: 2.2513x; 1.3748x over previous
//
#include <hip/hip_runtime.h>
#include <hip/hip_bf16.h>

typedef short bf16x8 __attribute__((ext_vector_type(8)));
typedef short bf16x4 __attribute__((ext_vector_type(4)));
typedef float f32x4 __attribute__((ext_vector_type(4)));
typedef unsigned short u16x8 __attribute__((ext_vector_type(8)));
typedef unsigned short u16x4 __attribute__((ext_vector_type(4)));

#define DEV static __device__ __forceinline__

DEV unsigned short f2bf(float f) {
  unsigned int u = __builtin_bit_cast(unsigned int, f);
  u += 0x7FFFu + ((u >> 16) & 1u);   // round-to-nearest-even
  return (unsigned short)(u >> 16);
}
DEV float bf2f(unsigned short u) {
  return __builtin_bit_cast(float, (unsigned int)u << 16);
}

DEV void gload_lds16(const unsigned short* g, unsigned short* l) {
  __builtin_amdgcn_global_load_lds(
      (const __attribute__((address_space(1))) unsigned int*)g,
      (__attribute__((address_space(3))) unsigned int*)l, 16, 0, 0);
}

DEV void waitv(int n) {   // n is compile-time under full unroll -> folds
  switch (n) {
    case 0: asm volatile("s_waitcnt vmcnt(0)" ::: "memory"); break;
    case 1: asm volatile("s_waitcnt vmcnt(1)" ::: "memory"); break;
    case 2: asm volatile("s_waitcnt vmcnt(2)" ::: "memory"); break;
    case 4: asm volatile("s_waitcnt vmcnt(4)" ::: "memory"); break;
    case 6: asm volatile("s_waitcnt vmcnt(6)" ::: "memory"); break;
    default: asm volatile("s_waitcnt vmcnt(0)" ::: "memory"); break;
  }
}

#define SB() __builtin_amdgcn_sched_barrier(0)
#define BAR() do { __builtin_amdgcn_s_barrier(); SB(); } while (0)
#define LBAR() do { asm volatile("s_waitcnt lgkmcnt(0)" ::: "memory"); \
                    SB(); \
                    __builtin_amdgcn_s_barrier(); \
                    SB(); } while (0)

// ---------------------------------------------------------------------------
// Convert pass: f32 -> bf16 for q,k,v (4M elems each) and Wq,Wk,Wv (1M each).
// ---------------------------------------------------------------------------
__global__ __launch_bounds__(256) void cvt_kernel(
    const float* __restrict__ q, const float* __restrict__ k,
    const float* __restrict__ v, const float* __restrict__ wq,
    const float* __restrict__ wk, const float* __restrict__ wv,
    unsigned short* __restrict__ xq, unsigned short* __restrict__ xk,
    unsigned short* __restrict__ xv, unsigned short* __restrict__ wqb,
    unsigned short* __restrict__ wkb, unsigned short* __restrict__ wvb)
{
  int tid = blockIdx.x * 256 + threadIdx.x;
  const float* src; unsigned short* dst; int off;
  if      (tid <  524288) { src = q;  dst = xq;  off = tid; }
  else if (tid < 1048576) { src = k;  dst = xk;  off = tid -  524288; }
  else if (tid < 1572864) { src = v;  dst = xv;  off = tid - 1048576; }
  else if (tid < 1703936) { src = wq; dst = wqb; off = tid - 1572864; }
  else if (tid < 1835008) { src = wk; dst = wkb; off = tid - 1703936; }
  else                    { src = wv; dst = wvb; off = tid - 1835008; }
  size_t e = (size_t)off * 8;
  float4 a = *(const float4*)(src + e);
  float4 b = *(const float4*)(src + e + 4);
  u16x8 p = { f2bf(a.x), f2bf(a.y), f2bf(a.z), f2bf(a.w),
              f2bf(b.x), f2bf(b.y), f2bf(b.z), f2bf(b.w) };
  *(u16x8*)(dst + e) = p;
}

// ---------------------------------------------------------------------------
// Fused projection GEMMs (unchanged): seg picks (X,W,bias,out,mode).
// ---------------------------------------------------------------------------
__global__ __launch_bounds__(512) void gemm_kernel(
    const unsigned short* __restrict__ xq, const unsigned short* __restrict__ xk,
    const unsigned short* __restrict__ xv, const unsigned short* __restrict__ wqb,
    const unsigned short* __restrict__ wkb, const unsigned short* __restrict__ wvb,
    const float* __restrict__ bq, const float* __restrict__ bk,
    const float* __restrict__ bv, unsigned short* __restrict__ qp,
    unsigned short* __restrict__ kp, unsigned short* __restrict__ vt)
{
  __shared__ union {
    struct { unsigned short A[128][64]; unsigned short B[128][64]; } ab;
    unsigned short T[128][128];
  } smu;
  const int t = threadIdx.x, lane = t & 63, wv8 = t >> 6;
  const int ln = lane & 15, g = lane >> 4;
  const int wm2 = wv8 >> 2, wn4 = wv8 & 3;
  const int seg = blockIdx.x >> 8, lb = blockIdx.x & 255;
  const int n0 = (lb & 7) * 128, m0 = (lb >> 3) * 128;

  const unsigned short* X; const unsigned short* W; const float* bias;
  unsigned short* outR; int mode;
  if (seg == 0)      { X = xq; W = wqb; bias = bq; outR = qp; mode = 0; }
  else if (seg == 1) { X = xk; W = wkb; bias = bk; outR = kp; mode = 0; }
  else               { X = xv; W = wvb; bias = bv; outR = vt; mode = 2; }

  f32x4 acc[4][2];
#pragma unroll
  for (int i = 0; i < 4; ++i)
#pragma unroll
    for (int j = 0; j < 2; ++j) acc[i][j] = {0.f, 0.f, 0.f, 0.f};

  const int lrow = lane >> 3, lcol = (lane & 7) * 8;
  for (int kt = 0; kt < 16; ++kt) {
    const int k0 = kt * 64;
    __syncthreads();
#pragma unroll
    for (int i = 0; i < 2; ++i) {
      const int r = wv8 * 16 + i * 8;
      gload_lds16(X + (size_t)(m0 + r + lrow) * 1024 + k0 + lcol, &smu.ab.A[r][0]);
      gload_lds16(W + (size_t)(n0 + r + lrow) * 1024 + k0 + lcol, &smu.ab.B[r][0]);
    }
    __syncthreads();
#pragma unroll
    for (int ks = 0; ks < 2; ++ks) {
      bf16x8 af[4], bfr[2];
#pragma unroll
      for (int i = 0; i < 4; ++i)
        af[i] = *(const bf16x8*)&smu.ab.A[wm2 * 64 + i * 16 + ln][ks * 32 + g * 8];
#pragma unroll
      for (int j = 0; j < 2; ++j)
        bfr[j] = *(const bf16x8*)&smu.ab.B[wn4 * 32 + j * 16 + ln][ks * 32 + g * 8];
#pragma unroll
      for (int i = 0; i < 4; ++i)
#pragma unroll
        for (int j = 0; j < 2; ++j)
          acc[i][j] = __builtin_amdgcn_mfma_f32_16x16x32_bf16(
              af[i], bfr[j], acc[i][j], 0, 0, 0);
    }
  }

  float bvv[2];
#pragma unroll
  for (int j = 0; j < 2; ++j) bvv[j] = bias[n0 + wn4 * 32 + j * 16 + ln];

  if (mode == 0) {
#pragma unroll
    for (int i = 0; i < 4; ++i)
#pragma unroll
      for (int j = 0; j < 2; ++j)
#pragma unroll
        for (int r = 0; r < 4; ++r) {
          int row = m0 + wm2 * 64 + i * 16 + g * 4 + r;
          int col = n0 + wn4 * 32 + j * 16 + ln;
          outR[(size_t)row * 1024 + col] = f2bf(acc[i][j][r] + bvv[j]);
        }
  } else {
    __syncthreads();
#pragma unroll
    for (int i = 0; i < 4; ++i)
#pragma unroll
      for (int j = 0; j < 2; ++j)
#pragma unroll
        for (int r = 0; r < 4; ++r)
          smu.T[wn4 * 32 + j * 16 + ln][wm2 * 64 + i * 16 + g * 4 + r] =
              f2bf(acc[i][j][r] + bvv[j]);
    __syncthreads();
    const int bb = m0 >> 10, l0 = m0 & 1023;
#pragma unroll
    for (int it = 0; it < 4; ++it) {
      const int col = it * 32 + (t >> 4);
      const int r8 = (t & 15) * 8;
      *(u16x8*)&outR[((size_t)(bb * 16 + (n0 >> 6) + (col >> 6)) * 64 + (col & 63)) * 1024 + l0 + r8] =
          *(const u16x8*)&smu.T[col][r8];
    }
  }
}

// ---------------------------------------------------------------------------
// Attention: block = (b, h, 32 q-rows), 512 threads = 8 waves (4 wq x 2 wm).
// S^T = K*Q^T (validated mapping). QK phase: PER-WAVE private K rings
// (8 x 3 x 2KB), zero barriers, self-paced counted vmcnt per wave.
// PV phase: shared 3-slot x 16KB V ring, 1 barrier/chunk, counted vmcnt,
// attention stores (2/chunk) interleaved into the loop with exact in-order
// vmcnt bookkeeping. Both-sides XOR swizzle throughout. Residual -> d_out.
// ---------------------------------------------------------------------------
__global__ __launch_bounds__(512, 2) void attn_kernel(
    const unsigned short* __restrict__ qp, const unsigned short* __restrict__ kp,
    const unsigned short* __restrict__ vt, const unsigned char* __restrict__ masks,
    float* __restrict__ attn_out, float* __restrict__ res_out)
{
  __shared__ union {
    unsigned short Kw[8][3][1024];   // per-wave K rings: [wave][slot][16*64]
    unsigned short Vb[3][64][128];   // shared V ring
    float ctxp[4][32][68];           // reduction phase (+4 pad: bank spread)
  } sm;
  __shared__ float red[2][2][16][4]; // [phase: max/sum][wm][ln][wq]

  const int t = threadIdx.x;
  const int wv = t >> 6, lane = t & 63;
  const int ln = lane & 15, g = lane >> 4;
  const int wq = wv & 3, wm = wv >> 2;
  const int hw = blockIdx.x;
  const int lid = (hw & 7) * 256 + (hw >> 3);  // cluster same-(b,h) per XCD
  const int b = lid >> 9, h = (lid >> 5) & 15, m0 = (lid & 31) * 32;
  const size_t rowbase = (size_t)(b * 1024 + m0);

  // ---- Q fragments (oldest vmcnt entries; retired by the first QK waits) ----
  bf16x8 qf[2];
  {
    const unsigned short* qb =
        qp + (rowbase + wm * 16 + ln) * 1024 + h * 64 + g * 8;
    qf[0] = *(const bf16x8*)qb;
    qf[1] = *(const bf16x8*)(qb + 32);
  }
  SB();

  // staging geometry
  const int slr8 = lane >> 3;                // 0..7 local row (K chunks)
  const int suK = (lane & 7) ^ slr8;         // swizzled K source unit
  const int vlr = lane >> 4;                 // 0..3 local row (V chunks)
  const int vu1 = (lane & 15) ^ vlr;         // V source units (rows +0..3)
  const int vu2 = (lane & 15) ^ (4 + vlr);   //               (rows +4..7)
  const unsigned short* kbase = kp + (size_t)b * 1048576 + h * 64;
  const unsigned short* vtb = vt + ((size_t)(b * 16 + h) * 64) * 1024;
  unsigned short* kwv = &sm.Kw[wv][0][0];

#define STAGE_K(tt) do { \
    gload_lds16(kbase + (size_t)((tt) * 64 + wq * 16 + slr8) * 1024 + suK * 8, \
                kwv + ((tt) % 3) * 1024); \
    gload_lds16(kbase + (size_t)((tt) * 64 + wq * 16 + 8 + slr8) * 1024 + suK * 8, \
                kwv + ((tt) % 3) * 1024 + 512); } while (0)
#define STAGE_V(c) do { \
    gload_lds16(vtb + (size_t)(wv * 8 + vlr) * 1024 + (c) * 128 + vu1 * 8, \
                &sm.Vb[(c) % 3][wv * 8][0]); \
    gload_lds16(vtb + (size_t)(wv * 8 + 4 + vlr) * 1024 + (c) * 128 + vu2 * 8, \
                &sm.Vb[(c) % 3][wv * 8 + 4][0]); } while (0)

  f32x4 sc[16];
#pragma unroll
  for (int i = 0; i < 16; ++i) sc[i] = {0.f, 0.f, 0.f, 0.f};

  // ---- QK^T: per-wave ring, NO barriers, self-paced counted vmcnt ----
  STAGE_K(0); STAGE_K(1);
  SB();
#pragma unroll
  for (int tt = 0; tt < 16; ++tt) {
    waitv(tt <= 14 ? 2 : 0);
    SB();
    if (tt + 2 < 16) STAGE_K(tt + 2);
    SB();
    const unsigned short* ksl = kwv + (tt % 3) * 1024 + ln * 64;
    bf16x8 kf0 = *(const bf16x8*)(ksl + (g ^ (ln & 7)) * 8);
    bf16x8 kf1 = *(const bf16x8*)(ksl + ((4 + g) ^ (ln & 7)) * 8);
    sc[tt] = __builtin_amdgcn_mfma_f32_16x16x32_bf16(kf0, qf[0], sc[tt], 0, 0, 0);
    sc[tt] = __builtin_amdgcn_mfma_f32_16x16x32_bf16(kf1, qf[1], sc[tt], 0, 0, 0);
  }

  // ---- mask loads (in flight while V stages issue / softmax starts) ----
  unsigned mw[16];
  {
    const unsigned char* mrow =
        masks + ((size_t)b * 1024 + m0 + wm * 16 + ln) * 1024 + wq * 16 + g * 4;
#pragma unroll
    for (int tt = 0; tt < 16; ++tt) mw[tt] = *(const unsigned*)(mrow + tt * 64);
  }
  SB();

  LBAR();                       // all waves past QK; K regions reusable for V
  STAGE_V(0); STAGE_V(1);       // V latency hides under softmax
  SB();

  // ---- softmax on raw scores (rows lane-local: q-row = ln) ----
  // max is invariant to the positive 1/sqrt(64) scale; fold it into exp2.
  const float C = 0.18033688011112042f;   // 0.125 * log2(e)
  float mx = -3.0e30f;
#pragma unroll
  for (int tt = 0; tt < 16; ++tt) {
    if (mw[tt]) {
#pragma unroll
      for (int r = 0; r < 4; ++r)
        if ((mw[tt] >> (8 * r)) & 0xffu) sc[tt][r] = -1.0e30f;
    }
#pragma unroll
    for (int r = 0; r < 4; ++r) mx = fmaxf(mx, sc[tt][r]);
  }
  mx = fmaxf(mx, __shfl_xor(mx, 16));
  mx = fmaxf(mx, __shfl_xor(mx, 32));
  if (g == 0) red[0][wm][ln][wq] = mx;
  LBAR();
  mx = fmaxf(fmaxf(red[0][wm][ln][0], red[0][wm][ln][1]),
             fmaxf(red[0][wm][ln][2], red[0][wm][ln][3]));
  const float mt = mx * C;

  float sum = 0.f;
#pragma unroll
  for (int tt = 0; tt < 16; ++tt)
#pragma unroll
    for (int r = 0; r < 4; ++r) {
      float p = exp2f(__builtin_fmaf(sc[tt][r], C, -mt));
      sc[tt][r] = p;
      sum += p;
    }
  sum += __shfl_xor(sum, 16);
  sum += __shfl_xor(sum, 32);
  if (g == 0) red[1][wm][ln][wq] = sum;
  LBAR();
  float l4 = red[1][wm][ln][0] + red[1][wm][ln][1] +
             red[1][wm][ln][2] + red[1][wm][ln][3];
  float rinv = 1.0f / l4;

  // ---- normalized bf16 P fragments (also the attention output values) ----
  bf16x8 af8[8];
#pragma unroll
  for (int c = 0; c < 8; ++c) {
    bf16x8 a;
#pragma unroll
    for (int r = 0; r < 4; ++r) a[r]     = (short)f2bf(sc[2 * c][r] * rinv);
#pragma unroll
    for (int r = 0; r < 4; ++r) a[4 + r] = (short)f2bf(sc[2 * c + 1][r] * rinv);
    af8[c] = a;
  }

  // ---- PV + interleaved attention stores ----
  // issue order/iter: [waitv][BAR][STAGE_V(c+2)][4 MFMA][2 stores]
  // in-order vmcnt: younger-than-V(c) = {2,4,6,6,6,6,6,4} for c=0..7
  f32x4 cacc[4];
#pragma unroll
  for (int i = 0; i < 4; ++i) cacc[i] = {0.f, 0.f, 0.f, 0.f};
  const size_t abase =
      ((size_t)(b * 16 + h) * 1024 + (m0 + wm * 16 + ln)) * 1024 + wq * 16 + g * 4;
#pragma unroll
  for (int c = 0; c < 8; ++c) {
    waitv(c == 0 ? 2 : (c == 1 ? 4 : (c <= 6 ? 6 : 4)));
    BAR();
    if (c + 2 < 8) STAGE_V(c + 2);
    SB();
#pragma unroll
    for (int ni = 0; ni < 4; ++ni) {
      const int d = ni * 16 + ln;
      const int u0 = (2 * wq + (g >> 1)) ^ (ln & 7);
      const int u1 = (8 + 2 * wq + (g >> 1)) ^ (ln & 7);
      bf16x4 b0 = *(const bf16x4*)&sm.Vb[c % 3][d][u0 * 8 + (g & 1) * 4];
      bf16x4 b1 = *(const bf16x4*)&sm.Vb[c % 3][d][u1 * 8 + (g & 1) * 4];
      bf16x8 bfr = { b0[0], b0[1], b0[2], b0[3], b1[0], b1[1], b1[2], b1[3] };
      cacc[ni] = __builtin_amdgcn_mfma_f32_16x16x32_bf16(af8[c], bfr, cacc[ni], 0, 0, 0);
    }
    SB();
#pragma unroll
    for (int hf = 0; hf < 2; ++hf) {
      f32x4 v = { bf2f((unsigned short)af8[c][hf * 4 + 0]),
                  bf2f((unsigned short)af8[c][hf * 4 + 1]),
                  bf2f((unsigned short)af8[c][hf * 4 + 2]),
                  bf2f((unsigned short)af8[c][hf * 4 + 3]) };
      *(f32x4*)(attn_out + abase + (2 * c + hf) * 64) = v;
    }
    SB();
  }

  // ---- cross-wave ctx reduction + residual -> d_out ----
  LBAR();                       // all Vb reads done; reuse as ctxp
#pragma unroll
  for (int ni = 0; ni < 4; ++ni)
#pragma unroll
    for (int r = 0; r < 4; ++r)
      sm.ctxp[wq][wm * 16 + g * 4 + r][ni * 16 + ln] = cacc[ni][r];
  LBAR();
  {
    const int m = t >> 4, d4 = (t & 15) * 4;
    f32x4 s0 = *(const f32x4*)&sm.ctxp[0][m][d4];
    f32x4 s1 = *(const f32x4*)&sm.ctxp[1][m][d4];
    f32x4 s2 = *(const f32x4*)&sm.ctxp[2][m][d4];
    f32x4 s3 = *(const f32x4*)&sm.ctxp[3][m][d4];
    f32x4 s = s0 + s1 + s2 + s3;
    const unsigned short* qrow = qp + (rowbase + m) * 1024 + h * 64 + d4;
    u16x4 qv = *(const u16x4*)qrow;
    f32x4 qf32 = { bf2f(qv[0]), bf2f(qv[1]), bf2f(qv[2]), bf2f(qv[3]) };
    s = s + qf32;
    *(f32x4*)(res_out + (rowbase + m) * 1024 + h * 64 + d4) = s;
  }
#undef STAGE_K
#undef STAGE_V
}

// ---------------------------------------------------------------------------
// In-place LayerNorm on d_out[:B*L*D]: out = LN(out) * g + b, one block/row.
// ---------------------------------------------------------------------------
__global__ __launch_bounds__(256) void ln_kernel(
    float* __restrict__ io,
    const float* __restrict__ gma, const float* __restrict__ bta)
{
  __shared__ float rbuf[2][4];
  const int r = blockIdx.x, t = threadIdx.x;
  const int i4 = t * 4;
  const size_t base = (size_t)r * 1024 + i4;
  f32x4 x = *(const f32x4*)(io + base);
  float s = x[0] + x[1] + x[2] + x[3];
  float q = x[0]*x[0] + x[1]*x[1] + x[2]*x[2] + x[3]*x[3];
#pragma unroll
  for (int off = 1; off < 64; off <<= 1) {
    s += __shfl_xor(s, off);
    q += __shfl_xor(q, off);
  }
  const int wv = t >> 6;
  if ((t & 63) == 0) { rbuf[0][wv] = s; rbuf[1][wv] = q; }
  __syncthreads();
  s = rbuf[0][0] + rbuf[0][1] + rbuf[0][2] + rbuf[0][3];
  q = rbuf[1][0] + rbuf[1][1] + rbuf[1][2] + rbuf[1][3];
  float mu = s * (1.0f / 1024.0f);
  float var = q * (1.0f / 1024.0f) - mu * mu;
  float is = rsqrtf(var + 1e-6f);
  f32x4 gv = *(const f32x4*)(gma + i4);
  f32x4 bv = *(const f32x4*)(bta + i4);
  f32x4 o;
#pragma unroll
  for (int k = 0; k < 4; ++k) o[k] = (x[k] - mu) * is * gv[k] + bv[k];
  *(f32x4*)(io + base) = o;
}

// ---------------------------------------------------------------------------
extern "C" void kernel_launch(void* const* d_in, const int* in_sizes, int n_in,
                              void* d_out, int out_size, void* d_ws, size_t ws_size,
                              hipStream_t stream) {
  const float* q  = (const float*)d_in[0];
  const float* k  = (const float*)d_in[1];
  const float* v  = (const float*)d_in[2];
  const unsigned char* masks = (const unsigned char*)d_in[3];
  const float* Wq = (const float*)d_in[4];
  const float* bq = (const float*)d_in[5];
  const float* Wk = (const float*)d_in[6];
  const float* bk = (const float*)d_in[7];
  const float* Wv = (const float*)d_in[8];
  const float* bv = (const float*)d_in[9];
  const float* lg = (const float*)d_in[10];
  const float* lb = (const float*)d_in[11];

  float* out = (float*)d_out;
  float* attn_out = out + (size_t)4 * 1024 * 1024;

  // bf16 input scratch lives in the attn region of d_out (overwritten later
  // by attn_kernel -- all reads happen in cvt/gemm, stream-ordered before).
  unsigned short* xq  = (unsigned short*)attn_out;
  unsigned short* xk  = xq + 4194304;
  unsigned short* xv  = xk + 4194304;
  unsigned short* wqb = xv + 4194304;
  unsigned short* wkb = wqb + 1048576;
  unsigned short* wvb = wkb + 1048576;

  // workspace: 24 MB (qp | kp | vt, all bf16 4M elems each)
  unsigned short* qp = (unsigned short*)d_ws;
  unsigned short* kp = qp + 4194304;
  unsigned short* vt = kp + 4194304;

  hipLaunchKernelGGL(cvt_kernel, dim3(7680), dim3(256), 0, stream,
                     q, k, v, Wq, Wk, Wv, xq, xk, xv, wqb, wkb, wvb);
  hipLaunchKernelGGL(gemm_kernel, dim3(768), dim3(512), 0, stream,
                     xq, xk, xv, wqb, wkb, wvb, bq, bk, bv, qp, kp, vt);
  hipLaunchKernelGGL(attn_kernel, dim3(2048), dim3(512), 0, stream,
                     qp, kp, vt, masks, attn_out, out);
  hipLaunchKernelGGL(ln_kernel, dim3(4096), dim3(256), 0, stream,
                     out, lg, lb);
}